// Round 4
// baseline (858.883 us; speedup 1.0000x reference)
//
#include <hip/hip_runtime.h>
#include <math.h>

#define H 128
#define NCLS 10
#define EPS 1e-5f
#define BN_BETA 1e-4f
#define CS_BLOCKS 256
#define ODC 32      // edge chunks for partial histograms
#define RNG_CAP 12544  // max bins per range (fits 50176B smem)

typedef unsigned short u16;
typedef unsigned int u32;
typedef __attribute__((ext_vector_type(8))) short short8;
typedef __attribute__((ext_vector_type(4))) float floatx4;

// ---- bf16 helpers (bit ops; RNE) ----
__device__ inline float bflo(u32 u) { union { u32 i; float f; } a; a.i = u << 16; return a.f; }
__device__ inline float bfhi(u32 u) { union { u32 i; float f; } a; a.i = u & 0xffff0000u; return a.f; }
__device__ inline u16 f2bf(float f) {
  union { float f; u32 i; } v; v.f = f;
  return (u16)((v.i + 0x7fff + ((v.i >> 16) & 1)) >> 16);
}
__device__ inline u32 pack2(float a, float b) { return (u32)f2bf(a) | ((u32)f2bf(b) << 16); }

// ---- latency-tolerant partial-row reduction: 8 independent streams ----------
__device__ inline void reduce_partials(const float* __restrict__ P, int nb, int stride,
                                       int off0, int f, float* su_out, float* sq_out) {
  float su[8] = {0, 0, 0, 0, 0, 0, 0, 0}, sq[8] = {0, 0, 0, 0, 0, 0, 0, 0};
  int b = 0;
  for (; b + 8 <= nb; b += 8) {
#pragma unroll
    for (int u = 0; u < 8; u++) {
      const float* p = P + (size_t)(b + u) * stride + off0;
      su[u] += p[f];
      sq[u] += p[128 + f];
    }
  }
  for (; b < nb; b++) {
    const float* p = P + (size_t)b * stride + off0;
    su[0] += p[f];
    sq[0] += p[128 + f];
  }
  *su_out = ((su[0] + su[1]) + (su[2] + su[3])) + ((su[4] + su[5]) + (su[6] + su[7]));
  *sq_out = ((sq[0] + sq[1]) + (sq[2] + sq[3])) + ((sq[4] + sq[5]) + (sq[6] + sq[7]));
}

// ---- fold body for 256 threads: 2 output columns per block -----------------
__device__ inline void fold256_body(const float* P, int nb, int stride, int off0,
                                    const float* W, const float* bias, float invN,
                                    int kp, u16* Wt, float* cf) {
  int f = threadIdx.x & 127;
  int half = threadIdx.x >> 7;
  int k = kp * 2 + half;
  float su, sq;
  reduce_partials(P, nb, stride, off0, f, &su, &sq);
  float mu = su * invN;
  float var = sq * invN - mu * mu;
  float s = 1.0f / sqrtf(fmaxf(var, 0.f) + EPS);
  float w = W[(size_t)f * H + k];
  Wt[(size_t)k * H + f] = f2bf(s * w);
  __shared__ float red[2][128];
  red[half][f] = (BN_BETA - mu * s) * w;
  __syncthreads();
  for (int o = 64; o > 0; o >>= 1) {
    if (f < o) red[half][f] += red[half][f + o];
    __syncthreads();
  }
  if (f == 0) cf[k] = red[half][0] + (bias ? bias[k] : 0.f);
}

// ================= small device bodies ======================================
// hist: ONLY in-side returning atomic (count + rank in one RMW)
__device__ inline void hist_body(const int* __restrict__ col, int E,
                                 int* cnt_in, int* rank_in, int blk) {
  int e = blk * 256 + threadIdx.x;
  if (e < E) rank_in[e] = atomicAdd(&cnt_in[col[e]], 1);
}

// out-degree partial histogram: block (r,c) counts rows of chunk c in range r (LDS)
__device__ inline void odpart_body(const int* __restrict__ row, int E, int N,
                                   int* __restrict__ partialOD, int RNG, int CE,
                                   int* bins, int blk) {
  int c = blk % ODC, r = blk / ODC;
  int lo = r * RNG;
  int hi = lo + RNG; if (hi > N) hi = N;
  int nb = hi - lo;
  for (int i = threadIdx.x; i < nb; i += 256) bins[i] = 0;
  __syncthreads();
  int e0 = c * CE, e1 = e0 + CE; if (e1 > E) e1 = E;
  for (int e = e0 + threadIdx.x; e < e1; e += 256) {
    int rr = row[e];
    if (rr >= lo && rr < hi) atomicAdd(&bins[rr - lo], 1);
  }
  __syncthreads();
  int* dst = partialOD + (size_t)c * N + lo;
  for (int i = threadIdx.x; i < nb; i += 256) dst[i] = bins[i];
}

// degc partial accumulation: float bins over att_e, same geometry
__device__ inline void degcpart_body(const int* __restrict__ row,
                                     const float* __restrict__ att_e, int E, int N,
                                     float* __restrict__ partialDC, int RNG, int CE,
                                     float* bins, int blk) {
  int c = blk % ODC, r = blk / ODC;
  int lo = r * RNG;
  int hi = lo + RNG; if (hi > N) hi = N;
  int nb = hi - lo;
  for (int i = threadIdx.x; i < nb; i += 256) bins[i] = 0.f;
  __syncthreads();
  int e0 = c * CE, e1 = e0 + CE; if (e1 > E) e1 = E;
  for (int e = e0 + threadIdx.x; e < e1; e += 256) {
    int rr = row[e];
    if (rr >= lo && rr < hi) atomicAdd(&bins[rr - lo], att_e[e]);
  }
  __syncthreads();
  float* dst = partialDC + (size_t)c * N + lo;
  for (int i = threadIdx.x; i < nb; i += 256) dst[i] = bins[i];
}

__device__ inline void xstats_body(const float* __restrict__ x, int n4,
                                   float* __restrict__ stp, int blk, float* smx) {
  int tid = threadIdx.x;
  int lane = tid & 63, wave = tid >> 6;
  float s[4] = {0, 0, 0, 0}, q[4] = {0, 0, 0, 0};
  int step = CS_BLOCKS * 256;
  for (int i = blk * 256 + tid; i < n4; i += step) {
    float4 v = ((const float4*)x)[i];
    s[0] += v.x; q[0] += v.x * v.x; s[1] += v.y; q[1] += v.y * v.y;
    s[2] += v.z; q[2] += v.z * v.z; s[3] += v.w; q[3] += v.w * v.w;
  }
#pragma unroll
  for (int k = 0; k < 4; k++) { s[k] += __shfl_xor(s[k], 32); q[k] += __shfl_xor(q[k], 32); }
  int col = (lane & 31) * 4;
  if (lane < 32) {
#pragma unroll
    for (int k = 0; k < 4; k++) {
      smx[wave * 256 + col + k] = s[k];
      smx[wave * 256 + 128 + col + k] = q[k];
    }
  }
  __syncthreads();
  stp[(size_t)blk * 256 + tid] =
      smx[tid] + smx[256 + tid] + smx[512 + tid] + smx[768 + tid];
}

// scanA: block sums of cnt_in + dinv/degS from out-degree partial reduce
__device__ inline void scanA_body(const int* cnt_in, const int* partialOD, int N,
                                  int* partial_in, float* dinv, int* degS, int blk) {
  int i = blk * 256 + threadIdx.x;
  if (i < N) {
    int vo = 0;
#pragma unroll 8
    for (int c = 0; c < ODC; c++) vo += partialOD[(size_t)c * N + i];
    dinv[i] = 1.0f / sqrtf((float)vo + 1.0f);
    degS[i] = vo;
  }
  __shared__ int sdA[256];
  sdA[threadIdx.x] = (i < N) ? cnt_in[i] : 0;
  __syncthreads();
  for (int o = 128; o > 0; o >>= 1) {
    if (threadIdx.x < o) sdA[threadIdx.x] += sdA[threadIdx.x + o];
    __syncthreads();
  }
  if (threadIdx.x == 0) partial_in[blk] = sdA[0];
}

__device__ inline void scanB1(const int* partial, int nb, int* blockoff) {
  __shared__ int sdB[256];
  int t = threadIdx.x;
  int v = (t < nb) ? partial[t] : 0;
  sdB[t] = v;
  __syncthreads();
  for (int o = 1; o < 256; o <<= 1) {
    int x = (t >= o) ? sdB[t - o] : 0;
    __syncthreads();
    sdB[t] += x;
    __syncthreads();
  }
  blockoff[t] = sdB[t] - v;
  __syncthreads();
}

__device__ inline void scanC1(const int* cnt, int N, const int* blockoff,
                              int* off, int E, int blk) {
  __shared__ int sdC[256];
  int t = threadIdx.x;
  int i = blk * 256 + t;
  int v = (i < N) ? cnt[i] : 0;
  sdC[t] = v;
  __syncthreads();
  for (int o = 1; o < 256; o <<= 1) {
    int x = (t >= o) ? sdC[t - o] : 0;
    __syncthreads();
    sdC[t] += x;
    __syncthreads();
  }
  if (i < N) off[i] = blockoff[blk] + sdC[t] - v;
  if (i == 0) off[N] = E;
  __syncthreads();
}

// non-atomic place via precomputed in-ranks
__device__ inline void place_body(const int* row, const int* col, int E,
                                  const int* rank_in, const int* off_in,
                                  const float* dinv, int* csr_src, int* slot_in,
                                  float* wn, int blk) {
  int e = blk * 256 + threadIdx.x;
  if (e < E) {
    int c = col[e], r = row[e];
    int si = off_in[c] + rank_in[e];
    csr_src[si] = r;
    slot_in[e] = si;
    wn[si] = dinv[r];
  }
}

// eatt: a0 into in-CSR order (att0s) + edge order (att_e); NO atomics
__device__ inline void eatt_body(const int* row, const int* col, int E,
                                 const float2* p01, const float2* q01,
                                 const float* b_ea, const int* slot_in,
                                 float* att0s, float* att_e, int blk) {
  int e = blk * 256 + threadIdx.x;
  if (e >= E) return;
  int r = row[e], c = col[e];
  float2 p = p01[r], q = q01[c];
  float l0 = p.x + q.x + b_ea[0];
  float l1 = p.y + q.y + b_ea[1];
  float a0 = 1.0f / (1.0f + expf(l1 - l0));
  att0s[slot_in[e]] = a0;
  att_e[e] = a0;
}

__device__ inline void xprestats_body(const u16* __restrict__ h,
                                      const float2* __restrict__ na01, int n4,
                                      float* __restrict__ stp, int blk) {
  int tid = threadIdx.x;
  int lane = tid & 63, wave = tid >> 6;
  float sc[4] = {0, 0, 0, 0}, qc[4] = {0, 0, 0, 0};
  float so[4] = {0, 0, 0, 0}, qo[4] = {0, 0, 0, 0};
  int step = CS_BLOCKS * 256;
  for (int i = blk * 256 + tid; i < n4; i += step) {
    int n = i >> 5;
    uint2 u = ((const uint2*)h)[i];
    float v0 = bflo(u.x), v1 = bfhi(u.x), v2 = bflo(u.y), v3 = bfhi(u.y);
    float2 ab = na01[n];
    float a = ab.x, b = ab.y;
    float c0 = v0 * a, c1 = v1 * a, c2 = v2 * a, c3 = v3 * a;
    float o0 = v0 * b, o1 = v1 * b, o2 = v2 * b, o3 = v3 * b;
    sc[0] += c0; qc[0] += c0 * c0; sc[1] += c1; qc[1] += c1 * c1;
    sc[2] += c2; qc[2] += c2 * c2; sc[3] += c3; qc[3] += c3 * c3;
    so[0] += o0; qo[0] += o0 * o0; so[1] += o1; qo[1] += o1 * o1;
    so[2] += o2; qo[2] += o2 * o2; so[3] += o3; qo[3] += o3 * o3;
  }
#pragma unroll
  for (int k = 0; k < 4; k++) {
    sc[k] += __shfl_xor(sc[k], 32); qc[k] += __shfl_xor(qc[k], 32);
    so[k] += __shfl_xor(so[k], 32); qo[k] += __shfl_xor(qo[k], 32);
  }
  __shared__ float smp[4][512];
  int col = (lane & 31) * 4;
  if (lane < 32) {
#pragma unroll
    for (int k = 0; k < 4; k++) {
      smp[wave][col + k] = sc[k];
      smp[wave][128 + col + k] = qc[k];
      smp[wave][256 + col + k] = so[k];
      smp[wave][384 + col + k] = qo[k];
    }
  }
  __syncthreads();
  float r0 = smp[0][tid] + smp[1][tid] + smp[2][tid] + smp[3][tid];
  float r1 = smp[0][256 + tid] + smp[1][256 + tid] + smp[2][256 + tid] + smp[3][256 + tid];
  stp[(size_t)blk * 512 + tid] = r0;
  stp[(size_t)blk * 512 + 256 + tid] = r1;
}

// ================= bf16 MFMA GEMM core ======================================
__device__ inline void gemm_core(const u16* A, const float* Afp, const u16* Bt,
                                 const float* cf, const float* b2, const float* sumw,
                                 u16* C, int N, int relu, int blk, float* stp) {
  int tid = threadIdx.x;
  int wave = tid >> 6, lane = tid & 63;
  int l15 = lane & 15, quad = lane >> 4;
  int row0 = (blk * 4 + wave) * 16;
  if (row0 >= N && !stp) return;
  int arow = row0 + l15;
  short8 a[4];
  short8 z8 = {0, 0, 0, 0, 0, 0, 0, 0};
  if (Afp) {
#pragma unroll
    for (int k4 = 0; k4 < 4; k4++) {
      if (arow < N) {
        const float* p = Afp + (size_t)arow * H + k4 * 32 + quad * 8;
        float4 f0 = *(const float4*)p;
        float4 f1 = *(const float4*)(p + 4);
        union { short8 s8; u32 u[4]; } cv;
        cv.u[0] = pack2(f0.x, f0.y); cv.u[1] = pack2(f0.z, f0.w);
        cv.u[2] = pack2(f1.x, f1.y); cv.u[3] = pack2(f1.z, f1.w);
        a[k4] = cv.s8;
      } else a[k4] = z8;
    }
  } else {
#pragma unroll
    for (int k4 = 0; k4 < 4; k4++)
      a[k4] = (arow < N) ? *(const short8*)(A + (size_t)arow * H + k4 * 32 + quad * 8) : z8;
  }
  float srow[4];
  if (sumw) {
#pragma unroll
    for (int r = 0; r < 4; r++) {
      int row = row0 + quad * 4 + r;
      srow[r] = (row < N) ? sumw[row] : 0.f;
    }
  }
  float ps[8], pq[8];
#pragma unroll
  for (int nt = 0; nt < 8; nt++) {
    floatx4 acc = {0.f, 0.f, 0.f, 0.f};
    const u16* bp = Bt + (size_t)(nt * 16 + l15) * H + quad * 8;
#pragma unroll
    for (int k4 = 0; k4 < 4; k4++) {
      short8 b = *(const short8*)(bp + k4 * 32);
      acc = __builtin_amdgcn_mfma_f32_16x16x32_bf16(a[k4], b, acc, 0, 0, 0);
    }
    int col = nt * 16 + l15;
    float base = cf[col];
    float bb = b2 ? b2[col] : 0.f;
    float s_ = 0.f, q_ = 0.f;
#pragma unroll
    for (int r = 0; r < 4; r++) {
      int row = row0 + quad * 4 + r;
      if (row < N) {
        float v = acc[r] + (sumw ? srow[r] * base + bb : base);
        if (relu) v = fmaxf(v, 0.f);
        s_ += v; q_ += v * v;
        C[(size_t)row * H + col] = f2bf(v);
      }
    }
    ps[nt] = s_; pq[nt] = q_;
  }
  if (stp) {
    __shared__ float sred[4][256];
#pragma unroll
    for (int nt = 0; nt < 8; nt++) {
      ps[nt] += __shfl_xor(ps[nt], 16); ps[nt] += __shfl_xor(ps[nt], 32);
      pq[nt] += __shfl_xor(pq[nt], 16); pq[nt] += __shfl_xor(pq[nt], 32);
    }
    if (quad == 0) {
#pragma unroll
      for (int nt = 0; nt < 8; nt++) {
        sred[wave][nt * 16 + l15] = ps[nt];
        sred[wave][128 + nt * 16 + l15] = pq[nt];
      }
    }
    __syncthreads();
    stp[(size_t)blk * 256 + tid] =
        sred[0][tid] + sred[1][tid] + sred[2][tid] + sred[3][tid];
  }
}

// ================= merged kernels ===========================================
__global__ __launch_bounds__(256) void hist_od_xstats_kernel(
    const int* row, const int* col, int E, int* cnt_in, int* rank_in, int gE,
    int N, int* partialOD, int RNG, int CE, int gOD,
    const float* x, int n4, float* stpX) {
  __shared__ __align__(16) char smem[50176];
  int b = blockIdx.x;
  if (b < gE)
    hist_body(col, E, cnt_in, rank_in, b);
  else if (b < gE + gOD)
    odpart_body(row, E, N, partialOD, RNG, CE, (int*)smem, b - gE);
  else
    xstats_body(x, n4, stpX, b - gE - gOD, (float*)smem);
}

__global__ __launch_bounds__(256) void scanA_fold_kernel(
    const int* cnt_in, const int* partialOD, int N, int* partial_in,
    float* dinv, int* degS, int SB, const float* stpX, const float* W_feat,
    const float* b_feat, float invN, u16* WtA, float* cfA) {
  if ((int)blockIdx.x < SB)
    scanA_body(cnt_in, partialOD, N, partial_in, dinv, degS, blockIdx.x);
  else
    fold256_body(stpX, CS_BLOCKS, 256, 0, W_feat, b_feat, invN, blockIdx.x - SB, WtA, cfA);
}

__global__ __launch_bounds__(256) void scanB_gemmx_kernel(
    const int* partial_in, int nb, int* blockoff_in,
    const float* x, const u16* WtA, const float* cfA, u16* C,
    int N, float* stpG) {
  if (blockIdx.x == 0) {
    scanB1(partial_in, nb, blockoff_in);
  } else {
    gemm_core(nullptr, x, WtA, cfA, nullptr, nullptr, C, N, 1, blockIdx.x - 1, stpG);
  }
}

__global__ __launch_bounds__(256) void scanC_fold_kernel(
    const int* cnt_in, int N, const int* blockoff_in, int* off_in, int E, int SB,
    const float* stpG, int nbG, const float* Wc, float invN, u16* WtB, float* cfB) {
  if ((int)blockIdx.x < SB) {
    scanC1(cnt_in, N, blockoff_in, off_in, E, blockIdx.x);
  } else {
    fold256_body(stpG, nbG, 256, 0, Wc, nullptr, invN, blockIdx.x - SB, WtB, cfB);
  }
}

__global__ __launch_bounds__(256) void place_gemm_kernel(
    const int* row, const int* col, int E, const int* rank_in,
    const int* off_in, const float* dinv, int* csr_src,
    int* slot_in, float* wn, int gE,
    const u16* A, const u16* WtB, const float* cfB, u16* C, int N) {
  if ((int)blockIdx.x < gE)
    place_body(row, col, E, rank_in, off_in, dinv, csr_src, slot_in, wn, blockIdx.x);
  else
    gemm_core(A, nullptr, WtB, cfB, nullptr, nullptr, C, N, 0, blockIdx.x - gE, nullptr);
}

__global__ __launch_bounds__(256) void eatt_xpre_kernel(
    const int* row, const int* col, int E, const float2* p01, const float2* q01,
    const float* b_ea, const int* slot_in, float* att0s, float* att_e,
    int gE, const u16* h, const float2* na01, int n4, float* stpPre) {
  if ((int)blockIdx.x < gE)
    eatt_body(row, col, E, p01, q01, b_ea, slot_in, att0s, att_e, blockIdx.x);
  else
    xprestats_body(h, na01, n4, stpPre, blockIdx.x - gE);
}

__global__ __launch_bounds__(256) void degcpart_fold2_kernel(
    const int* row, const float* att_e, int E, int N, float* partialDC,
    int RNG, int CE, int gDC,
    const float* stpPre, const float* W_ctx, const float* W_obj, float invN,
    u16* Wt2, float* cf2) {
  __shared__ __align__(16) char smem[50176];
  if ((int)blockIdx.x < gDC) {
    degcpart_body(row, att_e, E, N, partialDC, RNG, CE, (float*)smem, blockIdx.x);
  } else {
    int b = blockIdx.x - gDC;  // 0..127
    int j = b >> 6, kp = b & 63;
    fold256_body(stpPre, CS_BLOCKS, 512, j * 256, j ? W_obj : W_ctx, nullptr, invN, kp,
                 Wt2 + (size_t)j * H * H, cf2 + j * H);
  }
}

__global__ __launch_bounds__(256) void degc_reduce_kernel(
    const float* __restrict__ partialDC, float* __restrict__ degc, int N) {
  int i = blockIdx.x * 256 + threadIdx.x;
  if (i >= N) return;
  float s = 0.f;
#pragma unroll 8
  for (int c = 0; c < ODC; c++) s += partialDC[(size_t)c * N + i];
  degc[i] = s;
}

__global__ __launch_bounds__(256) void permadd_fold31_kernel(
    const u16* xc, const u16* xo, const int* perm, u16* outb, int n4, float* stpCO,
    const float* stpG, int nbG, const float* W_fc1, const float* b_fc1, float invN,
    u16* Wt3, float* cf3) {
  int tid = threadIdx.x;
  if ((int)blockIdx.x >= CS_BLOCKS) {
    int b = blockIdx.x - CS_BLOCKS;  // 0..127 -> heads 0,1
    int j = b >> 6, kp = b & 63;
    fold256_body(stpG + (size_t)j * nbG * 256, nbG, 256, 0, W_fc1 + (size_t)j * H * H,
                 b_fc1 + j * H, invN, kp, Wt3 + (size_t)j * H * H, cf3 + j * H);
    return;
  }
  int blk = blockIdx.x;
  int lane = tid & 63, wave = tid >> 6;
  float s[4] = {0, 0, 0, 0}, q[4] = {0, 0, 0, 0};
  int step = CS_BLOCKS * 256;
  for (int i = blk * 256 + tid; i < n4; i += step) {
    int n = i >> 5, k = i & 31;
    int p = perm[n];
    uint2 a = ((const uint2*)xc)[(size_t)p * 32 + k];
    uint2 b = ((const uint2*)xo)[i];
    float f0 = bflo(a.x) + bflo(b.x), f1 = bfhi(a.x) + bfhi(b.x);
    float f2 = bflo(a.y) + bflo(b.y), f3 = bfhi(a.y) + bfhi(b.y);
    ((uint2*)outb)[i] = make_uint2(pack2(f0, f1), pack2(f2, f3));
    s[0] += f0; q[0] += f0 * f0; s[1] += f1; q[1] += f1 * f1;
    s[2] += f2; q[2] += f2 * f2; s[3] += f3; q[3] += f3 * f3;
  }
#pragma unroll
  for (int k = 0; k < 4; k++) { s[k] += __shfl_xor(s[k], 32); q[k] += __shfl_xor(q[k], 32); }
  __shared__ float smq[4][256];
  int col = (lane & 31) * 4;
  if (lane < 32) {
#pragma unroll
    for (int k = 0; k < 4; k++) { smq[wave][col + k] = s[k]; smq[wave][128 + col + k] = q[k]; }
  }
  __syncthreads();
  stpCO[(size_t)blk * 256 + tid] = smq[0][tid] + smq[1][tid] + smq[2][tid] + smq[3][tid];
}

// ================= standalone kernels =======================================
__global__ __launch_bounds__(256) void fold256_kernel(
    const float* P, int nb, const float* W, const float* bias, float invN,
    u16* Wt, float* cf) {
  fold256_body(P, nb, 256, 0, W, bias, invN, blockIdx.x, Wt, cf);
}

__global__ __launch_bounds__(128) void fold10x3_kernel(
    const float* stpZ, int nb, const float* W_fc2, const float* b_fc2, float invN,
    float* W2f, float* c2f) {
  int j = blockIdx.x / NCLS, k = blockIdx.x % NCLS;
  const float* P = stpZ + (size_t)j * nb * 256;
  int f = threadIdx.x;
  float su, sq;
  reduce_partials(P, nb, 256, 0, f, &su, &sq);
  float mu = su * invN;
  float var = sq * invN - mu * mu;
  float s = 1.0f / sqrtf(fmaxf(var, 0.f) + EPS);
  float w = W_fc2[(size_t)j * H * NCLS + (size_t)f * NCLS + k];
  W2f[(size_t)j * H * NCLS + (size_t)f * NCLS + k] = s * w;
  __shared__ float red1[H];
  red1[f] = (BN_BETA - mu * s) * w;
  __syncthreads();
  for (int o = 64; o > 0; o >>= 1) {
    if (f < o) red1[f] += red1[f + o];
    __syncthreads();
  }
  if (f == 0) c2f[j * 16 + k] = red1[0] + b_fc2[j * NCLS + k];
}

__global__ __launch_bounds__(256) void gemm_kernel(
    const u16* A, const u16* Bt, const float* cf, u16* C, int N, int relu) {
  gemm_core(A, nullptr, Bt, cf, nullptr, nullptr, C, N, relu, blockIdx.x, nullptr);
}

__global__ __launch_bounds__(256) void gemm2sw_kernel(
    u16* B0, u16* B1, const u16* Wt2, const float* cf2,
    const float* b0, const float* b1, const float* sw0, const float* sw1,
    int N, int gG, float* stp) {
  int j = blockIdx.x / gG, blk = blockIdx.x % gG;
  u16* Z = j ? B1 : B0;
  gemm_core(Z, nullptr, Wt2 + (size_t)j * H * H, cf2 + j * H, j ? b1 : b0,
            j ? sw1 : sw0, Z, N, 1, blk, stp + (size_t)j * gG * 256);
}

__global__ __launch_bounds__(256) void gemm3_kernel(
    u16* Z0, u16* Z1, u16* Z2, const u16* Wt3, const float* cf3,
    int N, int gG, float* stp) {
  int j = blockIdx.x / gG, blk = blockIdx.x % gG;
  u16* Z = (j == 0) ? Z0 : (j == 1) ? Z1 : Z2;
  gemm_core(Z, nullptr, Wt3 + (size_t)j * H * H, cf3 + j * H, nullptr, nullptr,
            Z, N, 1, blk, stp + (size_t)j * gG * 256);
}

__global__ __launch_bounds__(256) void colstats_kernel(
    const u16* __restrict__ X, int N, float* __restrict__ stp) {
  int tid = threadIdx.x;
  int li = tid & 15, rg = tid >> 4;
  int wave = tid >> 6, lane = tid & 63;
  const uint4* T = (const uint4*)X;
  float s[8] = {0, 0, 0, 0, 0, 0, 0, 0}, q[8] = {0, 0, 0, 0, 0, 0, 0, 0};
  for (int r = blockIdx.x * 16 + rg; r < N; r += CS_BLOCKS * 16) {
    uint4 u = T[(size_t)r * 16 + li];
    float f[8] = {bflo(u.x), bfhi(u.x), bflo(u.y), bfhi(u.y),
                  bflo(u.z), bfhi(u.z), bflo(u.w), bfhi(u.w)};
#pragma unroll
    for (int j = 0; j < 8; j++) { s[j] += f[j]; q[j] += f[j] * f[j]; }
  }
#pragma unroll
  for (int j = 0; j < 8; j++) {
    s[j] += __shfl_xor(s[j], 16); s[j] += __shfl_xor(s[j], 32);
    q[j] += __shfl_xor(q[j], 16); q[j] += __shfl_xor(q[j], 32);
  }
  __shared__ float smc[4][256];
  if ((lane & 48) == 0) {
#pragma unroll
    for (int j = 0; j < 8; j++) {
      smc[wave][li * 8 + j] = s[j];
      smc[wave][128 + li * 8 + j] = q[j];
    }
  }
  __syncthreads();
  stp[(size_t)blockIdx.x * 256 + tid] = smc[0][tid] + smc[1][tid] + smc[2][tid] + smc[3][tid];
}

// ================= aggregation ==============================================
#define ACC8(A, U, W)                                             \
  A[0] += (W) * bflo(U.x); A[1] += (W) * bfhi(U.x);               \
  A[2] += (W) * bflo(U.y); A[3] += (W) * bfhi(U.y);               \
  A[4] += (W) * bflo(U.z); A[5] += (W) * bfhi(U.z);               \
  A[6] += (W) * bflo(U.w); A[7] += (W) * bfhi(U.w);

__global__ __launch_bounds__(256) void agg_kernel(
    const u16* __restrict__ t, const int* __restrict__ csr_src,
    const float* __restrict__ wseg, const int* __restrict__ off,
    const float* __restrict__ dinv, const float* __restrict__ bias,
    u16* __restrict__ out, int N) {
  int v = blockIdx.x * 4 + (threadIdx.x >> 6);
  if (v >= N) return;
  int lane = threadIdx.x & 63;
  int g = lane >> 4, li = lane & 15;
  const uint4* T = (const uint4*)t;
  float dv = dinv[v];
  float acc[8] = {0.f, 0.f, 0.f, 0.f, 0.f, 0.f, 0.f, 0.f};
  if (g == 0) {
    uint4 u = T[(size_t)v * 16 + li];
    float w0 = dv * dv;
    ACC8(acc, u, w0)
  }
  int s0 = off[v], s1 = off[v + 1];
  for (int s = s0; s < s1; s += 32) {
    int ix[8]; float wv[8];
#pragma unroll
    for (int u = 0; u < 8; u++) {
      int e = s + g + u * 4;
      bool ok = e < s1;
      int e2 = ok ? e : s0;
      ix[u] = csr_src[e2];
      wv[u] = ok ? wseg[e2] : 0.f;
    }
    uint4 uu[8];
#pragma unroll
    for (int u = 0; u < 8; u++) uu[u] = T[(size_t)ix[u] * 16 + li];
#pragma unroll
    for (int u = 0; u < 8; u++) { float w = wv[u] * dv; ACC8(acc, uu[u], w) }
  }
#pragma unroll
  for (int j = 0; j < 8; j++) {
    acc[j] += __shfl_xor(acc[j], 16);
    acc[j] += __shfl_xor(acc[j], 32);
  }
  if (g == 0) {
    float o[8];
#pragma unroll
    for (int j = 0; j < 8; j++) o[j] = fmaxf(acc[j] + bias[li * 8 + j], 0.f);
    uint4 w4;
    w4.x = pack2(o[0], o[1]); w4.y = pack2(o[2], o[3]);
    w4.z = pack2(o[4], o[5]); w4.w = pack2(o[6], o[7]);
    ((uint4*)out)[(size_t)v * 16 + li] = w4;
  }
}

// dual aggregation; edge weights computed inline from att0s/na01/degrees
__global__ __launch_bounds__(256) void aggdual_kernel(
    const u16* __restrict__ h, const int* __restrict__ csr_src,
    const float* __restrict__ att0s, const int* __restrict__ degS,
    const float* __restrict__ degc, const float2* __restrict__ na01,
    const int* __restrict__ off,
    u16* __restrict__ gc, u16* __restrict__ go,
    float* __restrict__ sumw_c, float* __restrict__ sumw_o, int N) {
  int v = blockIdx.x * 4 + (threadIdx.x >> 6);
  if (v >= N) return;
  int lane = threadIdx.x & 63;
  int g = lane >> 4, li = lane & 15;
  const uint4* T = (const uint4*)h;
  float dgc = degc[v];
  float dvc = 1.0f / sqrtf(dgc + 1.0f);
  float dvo = 1.0f / sqrtf((float)degS[v] - dgc + 1.0f);
  float ac[8] = {0.f, 0.f, 0.f, 0.f, 0.f, 0.f, 0.f, 0.f};
  float ao[8] = {0.f, 0.f, 0.f, 0.f, 0.f, 0.f, 0.f, 0.f};
  float swc = 0.f, swo = 0.f;
  if (g == 0) {
    uint4 u = T[(size_t)v * 16 + li];
    float2 na = na01[v];
    float wc = dvc * dvc, wo = dvo * dvo;
    float wch = wc * na.x, woh = wo * na.y;
    ACC8(ac, u, wch)
    ACC8(ao, u, woh)
  }
  int s0 = off[v], s1 = off[v + 1];
  for (int s = s0; s < s1; s += 16) {
    int ix[4]; float a0v[4];
#pragma unroll
    for (int u = 0; u < 4; u++) {
      int e = s + g + u * 4;
      bool ok = e < s1;
      int e2 = ok ? e : s0;
      ix[u] = csr_src[e2];
      a0v[u] = ok ? att0s[e2] : 0.f;
      if (!ok) a0v[u] = -1.f;  // sentinel: both weights zero
    }
    uint4 uu[4];
    float2 nav[4];
    float dS[4], dC[4];
#pragma unroll
    for (int u = 0; u < 4; u++) {
      int sidx = ix[u];
      uu[u] = T[(size_t)sidx * 16 + li];
      nav[u] = na01[sidx];
      dS[u] = (float)degS[sidx];
      dC[u] = degc[sidx];
    }
#pragma unroll
    for (int u = 0; u < 4; u++) {
      float a0 = a0v[u];
      bool ok = a0 >= 0.f;
      float r0 = ok ? a0 / sqrtf(dC[u] + 1.0f) : 0.f;
      float r1 = ok ? (1.0f - a0) / sqrtf(dS[u] - dC[u] + 1.0f) : 0.f;
      float wc = r0 * nav[u].x * dvc; ACC8(ac, uu[u], wc)
      float wo = r1 * nav[u].y * dvo; ACC8(ao, uu[u], wo)
      swc += r0; swo += r1;
    }
  }
#pragma unroll
  for (int j = 0; j < 8; j++) {
    ac[j] += __shfl_xor(ac[j], 16); ac[j] += __shfl_xor(ac[j], 32);
    ao[j] += __shfl_xor(ao[j], 16); ao[j] += __shfl_xor(ao[j], 32);
  }
  swc += __shfl_xor(swc, 16); swc += __shfl_xor(swc, 32);
  swo += __shfl_xor(swo, 16); swo += __shfl_xor(swo, 32);
  if (g == 0) {
    uint4 wc4, wo4;
    wc4.x = pack2(ac[0], ac[1]); wc4.y = pack2(ac[2], ac[3]);
    wc4.z = pack2(ac[4], ac[5]); wc4.w = pack2(ac[6], ac[7]);
    wo4.x = pack2(ao[0], ao[1]); wo4.y = pack2(ao[2], ao[3]);
    wo4.z = pack2(ao[4], ao[5]); wo4.w = pack2(ao[6], ao[7]);
    ((uint4*)gc)[(size_t)v * 16 + li] = wc4;
    ((uint4*)go)[(size_t)v * 16 + li] = wo4;
    if (li == 0) {
      sumw_c[v] = dvc * swc + dvc * dvc;
      sumw_o[v] = dvo * swo + dvo * dvo;
    }
  }
}

// ================= node attention + edge-att p,q factors =====================
__global__ __launch_bounds__(256) void natt_kernel(
    const u16* __restrict__ h, int N,
    const float* __restrict__ W_na, const float* __restrict__ b_na,
    const float* __restrict__ W_ea,
    float2* __restrict__ na01, float2* __restrict__ p01, float2* __restrict__ q01) {
  int n = blockIdx.x * 256 + threadIdx.x;
  if (n >= N) return;
  float sa0 = 0, sa1 = 0, sp0 = 0, sp1 = 0, sq0 = 0, sq1 = 0;
  const uint2* hr = (const uint2*)(h + (size_t)n * H);
  for (int c = 0; c < 32; c++) {
    uint2 u = hr[c];
    float v0 = bflo(u.x), v1 = bfhi(u.x), v2 = bflo(u.y), v3 = bfhi(u.y);
    int k = c * 4;
    sa0 += v0 * W_na[k * 2] + v1 * W_na[k * 2 + 2] + v2 * W_na[k * 2 + 4] + v3 * W_na[k * 2 + 6];
    sa1 += v0 * W_na[k * 2 + 1] + v1 * W_na[k * 2 + 3] + v2 * W_na[k * 2 + 5] + v3 * W_na[k * 2 + 7];
    sp0 += v0 * W_ea[k * 2] + v1 * W_ea[k * 2 + 2] + v2 * W_ea[k * 2 + 4] + v3 * W_ea[k * 2 + 6];
    sp1 += v0 * W_ea[k * 2 + 1] + v1 * W_ea[k * 2 + 3] + v2 * W_ea[k * 2 + 5] + v3 * W_ea[k * 2 + 7];
    sq0 += v0 * W_ea[(H + k) * 2] + v1 * W_ea[(H + k) * 2 + 2] + v2 * W_ea[(H + k) * 2 + 4] + v3 * W_ea[(H + k) * 2 + 6];
    sq1 += v0 * W_ea[(H + k) * 2 + 1] + v1 * W_ea[(H + k) * 2 + 3] + v2 * W_ea[(H + k) * 2 + 5] + v3 * W_ea[(H + k) * 2 + 7];
  }
  sa0 += b_na[0]; sa1 += b_na[1];
  float m = fmaxf(sa0, sa1);
  float e0 = expf(sa0 - m), e1 = expf(sa1 - m);
  float inv = 1.f / (e0 + e1);
  na01[n] = make_float2(e0 * inv, e1 * inv);
  p01[n] = make_float2(sp0, sp1);
  q01[n] = make_float2(sq0, sq1);
}

// ================= fc2 x3: [N,128]@[128,10] + log_softmax ====================
__global__ __launch_bounds__(256) void fc2x3_kernel(
    const u16* __restrict__ z0, const u16* __restrict__ z1, const u16* __restrict__ z2,
    const float* __restrict__ W2f, const float* __restrict__ c2f,
    float* __restrict__ outp, int N, int gN) {
  int j = blockIdx.x / gN, blk = blockIdx.x % gN;
  int n = blk * 256 + threadIdx.x;
  if (n >= N) return;
  const u16* z = (j == 0) ? z0 : (j == 1) ? z1 : z2;
  const float* W2 = W2f + (size_t)j * H * NCLS;
  const float* c2 = c2f + j * 16;
  float* op = outp + (size_t)j * N * NCLS;
  float acc[NCLS];
#pragma unroll
  for (int c = 0; c < NCLS; c++) acc[c] = c2[c];
  const uint2* zr = (const uint2*)(z + (size_t)n * H);
  for (int c4 = 0; c4 < 32; c4++) {
    uint2 u = zr[c4];
    float v[4] = {bflo(u.x), bfhi(u.x), bflo(u.y), bfhi(u.y)};
    int k = c4 * 4;
#pragma unroll
    for (int jj = 0; jj < 4; jj++)
#pragma unroll
      for (int c = 0; c < NCLS; c++) acc[c] += v[jj] * W2[(k + jj) * NCLS + c];
  }
  float m = acc[0];
#pragma unroll
  for (int c = 1; c < NCLS; c++) m = fmaxf(m, acc[c]);
  float s = 0.f;
#pragma unroll
  for (int c = 0; c < NCLS; c++) s += expf(acc[c] - m);
  float lse = logf(s) + m;
#pragma unroll
  for (int c = 0; c < NCLS; c++) op[(size_t)n * NCLS + c] = acc[c] - lse;
}

// =============================================================================
extern "C" void kernel_launch(void* const* d_in, const int* in_sizes, int n_in,
                              void* d_out, int out_size, void* d_ws, size_t ws_size,
                              hipStream_t stream) {
  const int N = in_sizes[0] / H;
  const int E = in_sizes[1] / 2;
  const float* x = (const float*)d_in[0];
  const int* ei = (const int*)d_in[1];
  const int* row = ei;
  const int* col = ei + E;
  const int* perm = (const int*)d_in[2];
  const float* W_feat = (const float*)d_in[3];
  const float* b_feat = (const float*)d_in[4];
  const float* W_convs = (const float*)d_in[5];
  const float* b_convs = (const float*)d_in[6];
  const float* W_ea = (const float*)d_in[7];
  const float* b_ea = (const float*)d_in[8];
  const float* W_na = (const float*)d_in[9];
  const float* b_na = (const float*)d_in[10];
  const float* W_ctx = (const float*)d_in[11];
  const float* b_ctx = (const float*)d_in[12];
  const float* W_obj = (const float*)d_in[13];
  const float* b_obj = (const float*)d_in[14];
  const float* W_fc1 = (const float*)d_in[15];
  const float* b_fc1 = (const float*)d_in[16];
  const float* W_fc2 = (const float*)d_in[17];
  const float* b_fc2 = (const float*)d_in[18];
  float* out = (float*)d_out;

  const int gG = (N + 63) / 64;
  const int gN = (N + 255) / 256;
  const int gE = (E + 255) / 256;
  const int SB = (N + 255) / 256;
  const int n4 = N * 32;
  const int gAgg = (N + 3) / 4;
  const float invN = 1.0f / (float)N;

  // partial-histogram geometry
  int R = (N + RNG_CAP - 1) / RNG_CAP; if (R < 1) R = 1;
  const int RNG = (N + R - 1) / R;
  const int CE = (E + ODC - 1) / ODC;
  const int gOD = R * ODC;

  // ---------- workspace carve ----------
  char* base = (char*)d_ws;
  size_t off_b = 0;
  auto alloc = [&](size_t bytes) -> void* {
    void* p = base + off_b;
    off_b = (off_b + bytes + 255) & ~(size_t)255;
    return p;
  };
  size_t NB2 = (size_t)N * H * sizeof(u16);
  u16* bufA = (u16*)alloc(NB2);  // h chain; hco; z2
  u16* bufB = (u16*)alloc(NB2);  // conv t temp
  u16* bufC = (u16*)alloc(NB2);  // gc -> xc -> z0
  u16* bufD = (u16*)alloc(NB2);  // go -> xo -> z1
  int* cnt_in = (int*)alloc((size_t)N * 4);       // memset target
  float* degc = (float*)alloc((size_t)N * 4);     // fully written by reduce
  int* degS = (int*)alloc((size_t)N * 4);
  int* partialOD = (int*)alloc((size_t)ODC * N * 4);
  float* partialDC = (float*)alloc((size_t)ODC * N * 4);
  float* stpX = (float*)alloc((size_t)CS_BLOCKS * 256 * 4);
  float* stpG = (float*)alloc(3 * (size_t)gG * 256 * 4);
  float* stpPre = (float*)alloc((size_t)CS_BLOCKS * 512 * 4);
  float* stpCO = (float*)alloc((size_t)CS_BLOCKS * 256 * 4);
  int* off_in = (int*)alloc(((size_t)N + 1) * 4);
  float* dinv = (float*)alloc((size_t)N * 4);
  float* sumw_c = (float*)alloc((size_t)N * 4);
  float* sumw_o = (float*)alloc((size_t)N * 4);
  float2* na01 = (float2*)alloc((size_t)N * 8);
  float2* p01 = (float2*)alloc((size_t)N * 8);
  float2* q01 = (float2*)alloc((size_t)N * 8);
  int* partial_in = (int*)alloc(256 * 4);
  int* blockoff_in = (int*)alloc(256 * 4);
  u16* WtA = (u16*)alloc((size_t)H * H * 2);
  u16* WtB = (u16*)alloc((size_t)H * H * 2);
  u16* Wt2 = (u16*)alloc(2 * (size_t)H * H * 2);
  u16* Wt3 = (u16*)alloc(3 * (size_t)H * H * 2);
  float* cfA = (float*)alloc(H * 4);
  float* cfB = (float*)alloc(H * 4);
  float* cf2 = (float*)alloc(2 * H * 4);
  float* cf3 = (float*)alloc(3 * H * 4);
  float* W2f = (float*)alloc(3 * (size_t)H * NCLS * 4);
  float* c2f = (float*)alloc(3 * 16 * 4);
  int* rank_in = (int*)alloc((size_t)E * 4);
  int* csr_src = (int*)alloc((size_t)E * 4);
  int* slot_in = (int*)alloc((size_t)E * 4);
  float* att0s = (float*)alloc((size_t)E * 4);
  float* att_e = (float*)alloc((size_t)E * 4);
  float* wn = (float*)alloc((size_t)E * 4);

  // 1. zero in-histogram only (out-degree & degc are atomic-free partials)
  hipMemsetAsync(cnt_in, 0, (size_t)N * 4, stream);

  // 2. hist-in(rank capture) || out-degree partials || xstats
  hist_od_xstats_kernel<<<gE + gOD + CS_BLOCKS, 256, 0, stream>>>(
      row, col, E, cnt_in, rank_in, gE, N, partialOD, RNG, CE, gOD, x, n4, stpX);
  // 3. scanA(in partials + dinv/degS from OD reduce) || fold(feat)
  scanA_fold_kernel<<<SB + 64, 256, 0, stream>>>(
      cnt_in, partialOD, N, partial_in, dinv, degS, SB, stpX, W_feat, b_feat,
      invN, WtA, cfA);
  // 4. scanB(in) || gemm_x
  scanB_gemmx_kernel<<<1 + gG, 256, 0, stream>>>(
      partial_in, SB, blockoff_in, x, WtA, cfA, bufA, N, stpG);
  // 5. scanC(in) || fold(conv0)
  scanC_fold_kernel<<<SB + 64, 256, 0, stream>>>(
      cnt_in, N, blockoff_in, off_in, E, SB, stpG, gG, W_convs, invN, WtB, cfB);
  // 6. place(non-atomic) || gemm(conv0: bufA -> bufB)
  place_gemm_kernel<<<gE + gG, 256, 0, stream>>>(
      row, col, E, rank_in, off_in, dinv, csr_src, slot_in, wn, gE,
      bufA, WtB, cfB, bufB, N);
  // 7. agg(conv0) -> h1 in bufA
  agg_kernel<<<gAgg, 256, 0, stream>>>(bufB, csr_src, wn, off_in, dinv, b_convs, bufA, N);

  // convs 1,2
  for (int i = 1; i < 3; ++i) {
    colstats_kernel<<<CS_BLOCKS, 256, 0, stream>>>(bufA, N, stpX);
    fold256_kernel<<<64, 256, 0, stream>>>(stpX, CS_BLOCKS, W_convs + (size_t)i * H * H,
                                           nullptr, invN, WtB, cfB);
    gemm_kernel<<<gG, 256, 0, stream>>>(bufA, WtB, cfB, bufB, N, 0);
    agg_kernel<<<gAgg, 256, 0, stream>>>(bufB, csr_src, wn, off_in, dinv,
                                         b_convs + (size_t)i * H, bufA, N);
  }

  // attention
  natt_kernel<<<gN, 256, 0, stream>>>(bufA, N, W_na, b_na, W_ea, na01, p01, q01);
  eatt_xpre_kernel<<<gE + CS_BLOCKS, 256, 0, stream>>>(
      row, col, E, p01, q01, b_ea, slot_in, att0s, att_e, gE,
      bufA, na01, n4, stpPre);
  // degc partials || fold2 (W_ctx/W_obj)
  degcpart_fold2_kernel<<<gOD + 128, 256, 0, stream>>>(
      row, att_e, E, N, partialDC, RNG, CE, gOD, stpPre, W_ctx, W_obj, invN, Wt2, cf2);
  degc_reduce_kernel<<<gN, 256, 0, stream>>>(partialDC, degc, N);
  aggdual_kernel<<<gAgg, 256, 0, stream>>>(bufA, csr_src, att0s, degS, degc, na01,
                                           off_in, bufC, bufD, sumw_c, sumw_o, N);
  gemm2sw_kernel<<<2 * gG, 256, 0, stream>>>(bufC, bufD, Wt2, cf2, b_ctx, b_obj,
                                             sumw_c, sumw_o, N, gG, stpG);
  // xc=bufC, xo=bufD; stats in stpG[0..2*gG)

  // h_co = xc[perm] + xo (+stats) || fold3 heads 0,1
  permadd_fold31_kernel<<<CS_BLOCKS + 128, 256, 0, stream>>>(
      bufC, bufD, perm, bufA, n4, stpCO, stpG, gG, W_fc1, b_fc1, invN, Wt3, cf3);
  // fold3 head 2 (stats from permadd)
  fold256_kernel<<<64, 256, 0, stream>>>(stpCO, CS_BLOCKS, W_fc1 + 2 * (size_t)H * H,
                                         b_fc1 + 2 * H, invN, Wt3 + 2 * (size_t)H * H,
                                         cf3 + 2 * H);
  gemm3_kernel<<<3 * gG, 256, 0, stream>>>(bufC, bufD, bufA, Wt3, cf3, N, gG, stpG);
  fold10x3_kernel<<<3 * NCLS, 128, 0, stream>>>(stpG, gG, W_fc2, b_fc2, invN, W2f, c2f);
  fc2x3_kernel<<<3 * gN, 256, 0, stream>>>(bufC, bufD, bufA, W2f, c2f, out, N, gN);
}

// Round 6
// 841.708 us; speedup vs baseline: 1.0204x; 1.0204x over previous
//
#include <hip/hip_runtime.h>
#include <math.h>

#define H 128
#define NCLS 10
#define EPS 1e-5f
#define BN_BETA 1e-4f
#define CS_BLOCKS 256

typedef unsigned short u16;
typedef unsigned int u32;
typedef __attribute__((ext_vector_type(8))) short short8;
typedef __attribute__((ext_vector_type(4))) float floatx4;

// ---- bf16 helpers (bit ops; RNE) ----
__device__ inline float bflo(u32 u) { union { u32 i; float f; } a; a.i = u << 16; return a.f; }
__device__ inline float bfhi(u32 u) { union { u32 i; float f; } a; a.i = u & 0xffff0000u; return a.f; }
__device__ inline u16 f2bf(float f) {
  union { float f; u32 i; } v; v.f = f;
  return (u16)((v.i + 0x7fff + ((v.i >> 16) & 1)) >> 16);
}
__device__ inline u32 pack2(float a, float b) { return (u32)f2bf(a) | ((u32)f2bf(b) << 16); }

// ---- latency-tolerant partial-row reduction: 8 independent streams ----------
__device__ inline void reduce_partials(const float* __restrict__ P, int nb, int stride,
                                       int off0, int f, float* su_out, float* sq_out) {
  float su[8] = {0, 0, 0, 0, 0, 0, 0, 0}, sq[8] = {0, 0, 0, 0, 0, 0, 0, 0};
  int b = 0;
  for (; b + 8 <= nb; b += 8) {
#pragma unroll
    for (int u = 0; u < 8; u++) {
      const float* p = P + (size_t)(b + u) * stride + off0;
      su[u] += p[f];
      sq[u] += p[128 + f];
    }
  }
  for (; b < nb; b++) {
    const float* p = P + (size_t)b * stride + off0;
    su[0] += p[f];
    sq[0] += p[128 + f];
  }
  *su_out = ((su[0] + su[1]) + (su[2] + su[3])) + ((su[4] + su[5]) + (su[6] + su[7]));
  *sq_out = ((sq[0] + sq[1]) + (sq[2] + sq[3])) + ((sq[4] + sq[5]) + (sq[6] + sq[7]));
}

// ---- fold body for 256 threads: 2 output columns per block -----------------
__device__ inline void fold256_body(const float* P, int nb, int stride, int off0,
                                    const float* W, const float* bias, float invN,
                                    int kp, u16* Wt, float* cf) {
  int f = threadIdx.x & 127;
  int half = threadIdx.x >> 7;
  int k = kp * 2 + half;
  float su, sq;
  reduce_partials(P, nb, stride, off0, f, &su, &sq);
  float mu = su * invN;
  float var = sq * invN - mu * mu;
  float s = 1.0f / sqrtf(fmaxf(var, 0.f) + EPS);
  float w = W[(size_t)f * H + k];
  Wt[(size_t)k * H + f] = f2bf(s * w);
  __shared__ float red[2][128];
  red[half][f] = (BN_BETA - mu * s) * w;
  __syncthreads();
  for (int o = 64; o > 0; o >>= 1) {
    if (f < o) red[half][f] += red[half][f + o];
    __syncthreads();
  }
  if (f == 0) cf[k] = red[half][0] + (bias ? bias[k] : 0.f);
}

// ================= small device bodies ======================================
// hist with rank capture: rank = old count (free slot assignment)
__device__ inline void hist_body(const int* __restrict__ row, const int* __restrict__ col,
                                 int E, int* cnt_in, int* cnt_out,
                                 int* rank_in, int* rank_out, int blk) {
  int e = blk * 256 + threadIdx.x;
  if (e < E) {
    rank_in[e] = atomicAdd(&cnt_in[col[e]], 1);
    rank_out[e] = atomicAdd(&cnt_out[row[e]], 1);
  }
}

__device__ inline void xstats_body(const float* __restrict__ x, int n4,
                                   float* __restrict__ stp, int blk) {
  int tid = threadIdx.x;
  int lane = tid & 63, wave = tid >> 6;
  float s[4] = {0, 0, 0, 0}, q[4] = {0, 0, 0, 0};
  int step = CS_BLOCKS * 256;
  for (int i = blk * 256 + tid; i < n4; i += step) {
    float4 v = ((const float4*)x)[i];
    s[0] += v.x; q[0] += v.x * v.x; s[1] += v.y; q[1] += v.y * v.y;
    s[2] += v.z; q[2] += v.z * v.z; s[3] += v.w; q[3] += v.w * v.w;
  }
#pragma unroll
  for (int k = 0; k < 4; k++) { s[k] += __shfl_xor(s[k], 32); q[k] += __shfl_xor(q[k], 32); }
  __shared__ float smx[4][256];
  int col = (lane & 31) * 4;
  if (lane < 32) {
#pragma unroll
    for (int k = 0; k < 4; k++) { smx[wave][col + k] = s[k]; smx[wave][128 + col + k] = q[k]; }
  }
  __syncthreads();
  stp[(size_t)blk * 256 + tid] = smx[0][tid] + smx[1][tid] + smx[2][tid] + smx[3][tid];
}

// scanA: block sums of cnt_in and cnt_out + dinv from out-degree
__device__ inline void scanA_body(const int* cnt_in, const int* cnt_out, int N,
                                  int* partial_in, int* partial_out, float* dinv, int blk) {
  int i = blk * 256 + threadIdx.x;
  int vo = (i < N) ? cnt_out[i] : 0;
  if (i < N) dinv[i] = 1.0f / sqrtf((float)vo + 1.0f);
  __shared__ int sdA[256];
  sdA[threadIdx.x] = (i < N) ? cnt_in[i] : 0;
  __syncthreads();
  for (int o = 128; o > 0; o >>= 1) {
    if (threadIdx.x < o) sdA[threadIdx.x] += sdA[threadIdx.x + o];
    __syncthreads();
  }
  if (threadIdx.x == 0) partial_in[blk] = sdA[0];
  __syncthreads();
  sdA[threadIdx.x] = vo;
  __syncthreads();
  for (int o = 128; o > 0; o >>= 1) {
    if (threadIdx.x < o) sdA[threadIdx.x] += sdA[threadIdx.x + o];
    __syncthreads();
  }
  if (threadIdx.x == 0) partial_out[blk] = sdA[0];
}

__device__ inline void scanB1(const int* partial, int nb, int* blockoff) {
  __shared__ int sdB[256];
  int t = threadIdx.x;
  int v = (t < nb) ? partial[t] : 0;
  sdB[t] = v;
  __syncthreads();
  for (int o = 1; o < 256; o <<= 1) {
    int x = (t >= o) ? sdB[t - o] : 0;
    __syncthreads();
    sdB[t] += x;
    __syncthreads();
  }
  blockoff[t] = sdB[t] - v;
  __syncthreads();
}

__device__ inline void scanC1(const int* cnt, int N, const int* blockoff,
                              int* off, int E, int blk) {
  __shared__ int sdC[256];
  int t = threadIdx.x;
  int i = blk * 256 + t;
  int v = (i < N) ? cnt[i] : 0;
  sdC[t] = v;
  __syncthreads();
  for (int o = 1; o < 256; o <<= 1) {
    int x = (t >= o) ? sdC[t - o] : 0;
    __syncthreads();
    sdC[t] += x;
    __syncthreads();
  }
  if (i < N) off[i] = blockoff[blk] + sdC[t] - v;
  if (i == 0) off[N] = E;
  __syncthreads();
}

// non-atomic place via precomputed ranks
__device__ inline void place_body(const int* row, const int* col, int E,
                                  const int* rank_in, const int* rank_out,
                                  const int* off_in, const int* off_out,
                                  const float* dinv, int* csr_src, int* slot_in,
                                  int* sout, float* wn, int blk) {
  int e = blk * 256 + threadIdx.x;
  if (e < E) {
    int c = col[e], r = row[e];
    int si = off_in[c] + rank_in[e];
    csr_src[si] = r;
    slot_in[e] = si;
    wn[si] = dinv[r];
    sout[e] = off_out[r] + rank_out[e];
  }
}

// eatt via dp/dq scalars (b_ea folded into dp): half the random gather bytes
__device__ inline void eatt_body(const int* row, const int* col, int E,
                                 const float* dp, const float* dq,
                                 const int* slot_in, const int* sout,
                                 float* att0s, float* att_r, int blk) {
  int e = blk * 256 + threadIdx.x;
  if (e >= E) return;
  float a0 = 1.0f / (1.0f + expf(-(dp[row[e]] + dq[col[e]])));
  att0s[slot_in[e]] = a0;
  att_r[sout[e]] = a0;
}

// degsum + per-node coefficient pack: f4 = (dvc, dvo, dvc*na.x, dvo*na.y)
__device__ inline void degsum_f4_body(const float* att_r, const int* off_out,
                                      const float2* na01, float4* f4, int N, int blk) {
  int v = blk * 256 + threadIdx.x;
  if (v >= N) return;
  int s0 = off_out[v], s1 = off_out[v + 1];
  float s = 0.f;
  for (int i = s0; i < s1; i++) s += att_r[i];
  float dvc = 1.0f / sqrtf(s + 1.0f);
  float dvo = 1.0f / sqrtf((float)(s1 - s0) - s + 1.0f);
  float2 na = na01[v];
  f4[v] = make_float4(dvc, dvo, dvc * na.x, dvo * na.y);
}

__device__ inline void xprestats_body(const u16* __restrict__ h,
                                      const float2* __restrict__ na01, int n4,
                                      float* __restrict__ stp, int blk) {
  int tid = threadIdx.x;
  int lane = tid & 63, wave = tid >> 6;
  float sc[4] = {0, 0, 0, 0}, qc[4] = {0, 0, 0, 0};
  float so[4] = {0, 0, 0, 0}, qo[4] = {0, 0, 0, 0};
  int step = CS_BLOCKS * 256;
  for (int i = blk * 256 + tid; i < n4; i += step) {
    int n = i >> 5;
    uint2 u = ((const uint2*)h)[i];
    float v0 = bflo(u.x), v1 = bfhi(u.x), v2 = bflo(u.y), v3 = bfhi(u.y);
    float2 ab = na01[n];
    float a = ab.x, b = ab.y;
    float c0 = v0 * a, c1 = v1 * a, c2 = v2 * a, c3 = v3 * a;
    float o0 = v0 * b, o1 = v1 * b, o2 = v2 * b, o3 = v3 * b;
    sc[0] += c0; qc[0] += c0 * c0; sc[1] += c1; qc[1] += c1 * c1;
    sc[2] += c2; qc[2] += c2 * c2; sc[3] += c3; qc[3] += c3 * c3;
    so[0] += o0; qo[0] += o0 * o0; so[1] += o1; qo[1] += o1 * o1;
    so[2] += o2; qo[2] += o2 * o2; so[3] += o3; qo[3] += o3 * o3;
  }
#pragma unroll
  for (int k = 0; k < 4; k++) {
    sc[k] += __shfl_xor(sc[k], 32); qc[k] += __shfl_xor(qc[k], 32);
    so[k] += __shfl_xor(so[k], 32); qo[k] += __shfl_xor(qo[k], 32);
  }
  __shared__ float smp[4][512];
  int col = (lane & 31) * 4;
  if (lane < 32) {
#pragma unroll
    for (int k = 0; k < 4; k++) {
      smp[wave][col + k] = sc[k];
      smp[wave][128 + col + k] = qc[k];
      smp[wave][256 + col + k] = so[k];
      smp[wave][384 + col + k] = qo[k];
    }
  }
  __syncthreads();
  float r0 = smp[0][tid] + smp[1][tid] + smp[2][tid] + smp[3][tid];
  float r1 = smp[0][256 + tid] + smp[1][256 + tid] + smp[2][256 + tid] + smp[3][256 + tid];
  stp[(size_t)blk * 512 + tid] = r0;
  stp[(size_t)blk * 512 + 256 + tid] = r1;
}

// ================= bf16 MFMA GEMM core ======================================
__device__ inline void gemm_core(const u16* A, const float* Afp, const u16* Bt,
                                 const float* cf, const float* b2, const float* sumw,
                                 u16* C, int N, int relu, int blk, float* stp) {
  int tid = threadIdx.x;
  int wave = tid >> 6, lane = tid & 63;
  int l15 = lane & 15, quad = lane >> 4;
  int row0 = (blk * 4 + wave) * 16;
  if (row0 >= N && !stp) return;
  int arow = row0 + l15;
  short8 a[4];
  short8 z8 = {0, 0, 0, 0, 0, 0, 0, 0};
  if (Afp) {
#pragma unroll
    for (int k4 = 0; k4 < 4; k4++) {
      if (arow < N) {
        const float* p = Afp + (size_t)arow * H + k4 * 32 + quad * 8;
        float4 f0 = *(const float4*)p;
        float4 f1 = *(const float4*)(p + 4);
        union { short8 s8; u32 u[4]; } cv;
        cv.u[0] = pack2(f0.x, f0.y); cv.u[1] = pack2(f0.z, f0.w);
        cv.u[2] = pack2(f1.x, f1.y); cv.u[3] = pack2(f1.z, f1.w);
        a[k4] = cv.s8;
      } else a[k4] = z8;
    }
  } else {
#pragma unroll
    for (int k4 = 0; k4 < 4; k4++)
      a[k4] = (arow < N) ? *(const short8*)(A + (size_t)arow * H + k4 * 32 + quad * 8) : z8;
  }
  float srow[4];
  if (sumw) {
#pragma unroll
    for (int r = 0; r < 4; r++) {
      int row = row0 + quad * 4 + r;
      srow[r] = (row < N) ? sumw[row] : 0.f;
    }
  }
  float ps[8], pq[8];
#pragma unroll
  for (int nt = 0; nt < 8; nt++) {
    floatx4 acc = {0.f, 0.f, 0.f, 0.f};
    const u16* bp = Bt + (size_t)(nt * 16 + l15) * H + quad * 8;
#pragma unroll
    for (int k4 = 0; k4 < 4; k4++) {
      short8 b = *(const short8*)(bp + k4 * 32);
      acc = __builtin_amdgcn_mfma_f32_16x16x32_bf16(a[k4], b, acc, 0, 0, 0);
    }
    int col = nt * 16 + l15;
    float base = cf[col];
    float bb = b2 ? b2[col] : 0.f;
    float s_ = 0.f, q_ = 0.f;
#pragma unroll
    for (int r = 0; r < 4; r++) {
      int row = row0 + quad * 4 + r;
      if (row < N) {
        float v = acc[r] + (sumw ? srow[r] * base + bb : base);
        if (relu) v = fmaxf(v, 0.f);
        s_ += v; q_ += v * v;
        C[(size_t)row * H + col] = f2bf(v);
      }
    }
    ps[nt] = s_; pq[nt] = q_;
  }
  if (stp) {
    __shared__ float sred[4][256];
#pragma unroll
    for (int nt = 0; nt < 8; nt++) {
      ps[nt] += __shfl_xor(ps[nt], 16); ps[nt] += __shfl_xor(ps[nt], 32);
      pq[nt] += __shfl_xor(pq[nt], 16); pq[nt] += __shfl_xor(pq[nt], 32);
    }
    if (quad == 0) {
#pragma unroll
      for (int nt = 0; nt < 8; nt++) {
        sred[wave][nt * 16 + l15] = ps[nt];
        sred[wave][128 + nt * 16 + l15] = pq[nt];
      }
    }
    __syncthreads();
    stp[(size_t)blk * 256 + tid] =
        sred[0][tid] + sred[1][tid] + sred[2][tid] + sred[3][tid];
  }
}

// ================= merged kernels ===========================================
__global__ __launch_bounds__(256) void hist_xstats_kernel(
    const int* row, const int* col, int E, int* cnt_in, int* cnt_out,
    int* rank_in, int* rank_out, int gE, const float* x, int n4, float* stpX) {
  if ((int)blockIdx.x < gE)
    hist_body(row, col, E, cnt_in, cnt_out, rank_in, rank_out, blockIdx.x);
  else
    xstats_body(x, n4, stpX, blockIdx.x - gE);
}

__global__ __launch_bounds__(256) void scanA_fold_kernel(
    const int* cnt_in, const int* cnt_out, int N, int* partial_in, int* partial_out,
    float* dinv, int SB, const float* stpX, const float* W_feat, const float* b_feat,
    float invN, u16* WtA, float* cfA) {
  if ((int)blockIdx.x < SB)
    scanA_body(cnt_in, cnt_out, N, partial_in, partial_out, dinv, blockIdx.x);
  else
    fold256_body(stpX, CS_BLOCKS, 256, 0, W_feat, b_feat, invN, blockIdx.x - SB, WtA, cfA);
}

__global__ __launch_bounds__(256) void scanB_gemmx_kernel(
    const int* partial_in, const int* partial_out, int nb, int* blockoff_in,
    int* blockoff_out, const float* x, const u16* WtA, const float* cfA, u16* C,
    int N, float* stpG) {
  if (blockIdx.x == 0) {
    scanB1(partial_in, nb, blockoff_in);
    scanB1(partial_out, nb, blockoff_out);
  } else {
    gemm_core(nullptr, x, WtA, cfA, nullptr, nullptr, C, N, 1, blockIdx.x - 1, stpG);
  }
}

__global__ __launch_bounds__(256) void scanC_fold_kernel(
    const int* cnt_in, const int* cnt_out, int N, const int* blockoff_in,
    const int* blockoff_out, int* off_in, int* off_out, int E, int SB,
    const float* stpG, int nbG, const float* Wc, float invN, u16* WtB, float* cfB) {
  if ((int)blockIdx.x < SB) {
    scanC1(cnt_in, N, blockoff_in, off_in, E, blockIdx.x);
    scanC1(cnt_out, N, blockoff_out, off_out, E, blockIdx.x);
  } else {
    fold256_body(stpG, nbG, 256, 0, Wc, nullptr, invN, blockIdx.x - SB, WtB, cfB);
  }
}

__global__ __launch_bounds__(256) void place_gemm_kernel(
    const int* row, const int* col, int E, const int* rank_in, const int* rank_out,
    const int* off_in, const int* off_out, const float* dinv, int* csr_src,
    int* slot_in, int* sout, float* wn, int gE,
    const u16* A, const u16* WtB, const float* cfB, u16* C, int N) {
  if ((int)blockIdx.x < gE)
    place_body(row, col, E, rank_in, rank_out, off_in, off_out, dinv, csr_src,
               slot_in, sout, wn, blockIdx.x);
  else
    gemm_core(A, nullptr, WtB, cfB, nullptr, nullptr, C, N, 0, blockIdx.x - gE, nullptr);
}

__global__ __launch_bounds__(256) void eatt_xpre_kernel(
    const int* row, const int* col, int E, const float* dp, const float* dq,
    const int* slot_in, const int* sout, float* att0s,
    float* att_r, int gE, const u16* h, const float2* na01, int n4, float* stpPre) {
  if ((int)blockIdx.x < gE)
    eatt_body(row, col, E, dp, dq, slot_in, sout, att0s, att_r, blockIdx.x);
  else
    xprestats_body(h, na01, n4, stpPre, blockIdx.x - gE);
}

__global__ __launch_bounds__(256) void degsum_fold2_kernel(
    const float* att_r, const int* off_out, const float2* na01, float4* f4,
    int N, int gN,
    const float* stpPre, const float* W_ctx, const float* W_obj, float invN,
    u16* Wt2, float* cf2) {
  if ((int)blockIdx.x < gN)
    degsum_f4_body(att_r, off_out, na01, f4, N, blockIdx.x);
  else {
    int b = blockIdx.x - gN;  // 0..127
    int j = b >> 6, kp = b & 63;
    fold256_body(stpPre, CS_BLOCKS, 512, j * 256, j ? W_obj : W_ctx, nullptr, invN, kp,
                 Wt2 + (size_t)j * H * H, cf2 + j * H);
  }
}

__global__ __launch_bounds__(256) void permadd_fold31_kernel(
    const u16* xc, const u16* xo, const int* perm, u16* outb, int n4, float* stpCO,
    const float* stpG, int nbG, const float* W_fc1, const float* b_fc1, float invN,
    u16* Wt3, float* cf3) {
  int tid = threadIdx.x;
  if ((int)blockIdx.x >= CS_BLOCKS) {
    int b = blockIdx.x - CS_BLOCKS;  // 0..127 -> heads 0,1
    int j = b >> 6, kp = b & 63;
    fold256_body(stpG + (size_t)j * nbG * 256, nbG, 256, 0, W_fc1 + (size_t)j * H * H,
                 b_fc1 + j * H, invN, kp, Wt3 + (size_t)j * H * H, cf3 + j * H);
    return;
  }
  int blk = blockIdx.x;
  int lane = tid & 63, wave = tid >> 6;
  float s[4] = {0, 0, 0, 0}, q[4] = {0, 0, 0, 0};
  int step = CS_BLOCKS * 256;
  for (int i = blk * 256 + tid; i < n4; i += step) {
    int n = i >> 5, k = i & 31;
    int p = perm[n];
    uint2 a = ((const uint2*)xc)[(size_t)p * 32 + k];
    uint2 b = ((const uint2*)xo)[i];
    float f0 = bflo(a.x) + bflo(b.x), f1 = bfhi(a.x) + bfhi(b.x);
    float f2 = bflo(a.y) + bflo(b.y), f3 = bfhi(a.y) + bfhi(b.y);
    ((uint2*)outb)[i] = make_uint2(pack2(f0, f1), pack2(f2, f3));
    s[0] += f0; q[0] += f0 * f0; s[1] += f1; q[1] += f1 * f1;
    s[2] += f2; q[2] += f2 * f2; s[3] += f3; q[3] += f3 * f3;
  }
#pragma unroll
  for (int k = 0; k < 4; k++) { s[k] += __shfl_xor(s[k], 32); q[k] += __shfl_xor(q[k], 32); }
  __shared__ float smq[4][256];
  int col = (lane & 31) * 4;
  if (lane < 32) {
#pragma unroll
    for (int k = 0; k < 4; k++) { smq[wave][col + k] = s[k]; smq[wave][128 + col + k] = q[k]; }
  }
  __syncthreads();
  stpCO[(size_t)blk * 256 + tid] = smq[0][tid] + smq[1][tid] + smq[2][tid] + smq[3][tid];
}

// ================= standalone kernels =======================================
__global__ __launch_bounds__(256) void fold256_kernel(
    const float* P, int nb, const float* W, const float* bias, float invN,
    u16* Wt, float* cf) {
  fold256_body(P, nb, 256, 0, W, bias, invN, blockIdx.x, Wt, cf);
}

__global__ __launch_bounds__(128) void fold10x3_kernel(
    const float* stpZ, int nb, const float* W_fc2, const float* b_fc2, float invN,
    float* W2f, float* c2f) {
  int j = blockIdx.x / NCLS, k = blockIdx.x % NCLS;
  const float* P = stpZ + (size_t)j * nb * 256;
  int f = threadIdx.x;
  float su, sq;
  reduce_partials(P, nb, 256, 0, f, &su, &sq);
  float mu = su * invN;
  float var = sq * invN - mu * mu;
  float s = 1.0f / sqrtf(fmaxf(var, 0.f) + EPS);
  float w = W_fc2[(size_t)j * H * NCLS + (size_t)f * NCLS + k];
  W2f[(size_t)j * H * NCLS + (size_t)f * NCLS + k] = s * w;
  __shared__ float red1[H];
  red1[f] = (BN_BETA - mu * s) * w;
  __syncthreads();
  for (int o = 64; o > 0; o >>= 1) {
    if (f < o) red1[f] += red1[f + o];
    __syncthreads();
  }
  if (f == 0) c2f[j * 16 + k] = red1[0] + b_fc2[j * NCLS + k];
}

__global__ __launch_bounds__(256) void gemm_kernel(
    const u16* A, const u16* Bt, const float* cf, u16* C, int N, int relu) {
  gemm_core(A, nullptr, Bt, cf, nullptr, nullptr, C, N, relu, blockIdx.x, nullptr);
}

__global__ __launch_bounds__(256) void gemm2sw_kernel(
    u16* B0, u16* B1, const u16* Wt2, const float* cf2,
    const float* b0, const float* b1, const float* sw0, const float* sw1,
    int N, int gG, float* stp) {
  int j = blockIdx.x / gG, blk = blockIdx.x % gG;
  u16* Z = j ? B1 : B0;
  gemm_core(Z, nullptr, Wt2 + (size_t)j * H * H, cf2 + j * H, j ? b1 : b0,
            j ? sw1 : sw0, Z, N, 1, blk, stp + (size_t)j * gG * 256);
}

__global__ __launch_bounds__(256) void gemm3_kernel(
    u16* Z0, u16* Z1, u16* Z2, const u16* Wt3, const float* cf3,
    int N, int gG, float* stp) {
  int j = blockIdx.x / gG, blk = blockIdx.x % gG;
  u16* Z = (j == 0) ? Z0 : (j == 1) ? Z1 : Z2;
  gemm_core(Z, nullptr, Wt3 + (size_t)j * H * H, cf3 + j * H, nullptr, nullptr,
            Z, N, 1, blk, stp + (size_t)j * gG * 256);
}

__global__ __launch_bounds__(256) void colstats_kernel(
    const u16* __restrict__ X, int N, float* __restrict__ stp) {
  int tid = threadIdx.x;
  int li = tid & 15, rg = tid >> 4;
  int wave = tid >> 6, lane = tid & 63;
  const uint4* T = (const uint4*)X;
  float s[8] = {0, 0, 0, 0, 0, 0, 0, 0}, q[8] = {0, 0, 0, 0, 0, 0, 0, 0};
  for (int r = blockIdx.x * 16 + rg; r < N; r += CS_BLOCKS * 16) {
    uint4 u = T[(size_t)r * 16 + li];
    float f[8] = {bflo(u.x), bfhi(u.x), bflo(u.y), bfhi(u.y),
                  bflo(u.z), bfhi(u.z), bflo(u.w), bfhi(u.w)};
#pragma unroll
    for (int j = 0; j < 8; j++) { s[j] += f[j]; q[j] += f[j] * f[j]; }
  }
#pragma unroll
  for (int j = 0; j < 8; j++) {
    s[j] += __shfl_xor(s[j], 16); s[j] += __shfl_xor(s[j], 32);
    q[j] += __shfl_xor(q[j], 16); q[j] += __shfl_xor(q[j], 32);
  }
  __shared__ float smc[4][256];
  if ((lane & 48) == 0) {
#pragma unroll
    for (int j = 0; j < 8; j++) {
      smc[wave][li * 8 + j] = s[j];
      smc[wave][128 + li * 8 + j] = q[j];
    }
  }
  __syncthreads();
  stp[(size_t)blockIdx.x * 256 + tid] = smc[0][tid] + smc[1][tid] + smc[2][tid] + smc[3][tid];
}

// ================= aggregation ==============================================
#define ACC8(A, U, W)                                             \
  A[0] += (W) * bflo(U.x); A[1] += (W) * bfhi(U.x);               \
  A[2] += (W) * bflo(U.y); A[3] += (W) * bfhi(U.y);               \
  A[4] += (W) * bflo(U.z); A[5] += (W) * bfhi(U.z);               \
  A[6] += (W) * bflo(U.w); A[7] += (W) * bfhi(U.w);

__global__ __launch_bounds__(256) void agg_kernel(
    const u16* __restrict__ t, const int* __restrict__ csr_src,
    const float* __restrict__ wseg, const int* __restrict__ off,
    const float* __restrict__ dinv, const float* __restrict__ bias,
    u16* __restrict__ out, int N) {
  int v = blockIdx.x * 4 + (threadIdx.x >> 6);
  if (v >= N) return;
  int lane = threadIdx.x & 63;
  int g = lane >> 4, li = lane & 15;
  const uint4* T = (const uint4*)t;
  float dv = dinv[v];
  float acc[8] = {0.f, 0.f, 0.f, 0.f, 0.f, 0.f, 0.f, 0.f};
  if (g == 0) {
    uint4 u = T[(size_t)v * 16 + li];
    float w0 = dv * dv;
    ACC8(acc, u, w0)
  }
  int s0 = off[v], s1 = off[v + 1];
  for (int s = s0; s < s1; s += 32) {
    int ix[8]; float wv[8];
#pragma unroll
    for (int u = 0; u < 8; u++) {
      int e = s + g + u * 4;
      bool ok = e < s1;
      int e2 = ok ? e : s0;
      ix[u] = csr_src[e2];
      wv[u] = ok ? wseg[e2] : 0.f;
    }
    uint4 uu[8];
#pragma unroll
    for (int u = 0; u < 8; u++) uu[u] = T[(size_t)ix[u] * 16 + li];
#pragma unroll
    for (int u = 0; u < 8; u++) { float w = wv[u] * dv; ACC8(acc, uu[u], w) }
  }
#pragma unroll
  for (int j = 0; j < 8; j++) {
    acc[j] += __shfl_xor(acc[j], 16);
    acc[j] += __shfl_xor(acc[j], 32);
  }
  if (g == 0) {
    float o[8];
#pragma unroll
    for (int j = 0; j < 8; j++) o[j] = fmaxf(acc[j] + bias[li * 8 + j], 0.f);
    uint4 w4;
    w4.x = pack2(o[0], o[1]); w4.y = pack2(o[2], o[3]);
    w4.z = pack2(o[4], o[5]); w4.w = pack2(o[6], o[7]);
    ((uint4*)out)[(size_t)v * 16 + li] = w4;
  }
}

// agg for the last conv + fused node-attention / edge-attention factors.
// All lanes hold the reduced row; 6 dot products via 4 shfl_xor replace the
// separate natt kernel (saves a full 12.8MB re-read dispatch).
__global__ __launch_bounds__(256) void agg_natt_kernel(
    const u16* __restrict__ t, const int* __restrict__ csr_src,
    const float* __restrict__ wseg, const int* __restrict__ off,
    const float* __restrict__ dinv, const float* __restrict__ bias,
    const float* __restrict__ W_na, const float* __restrict__ b_na,
    const float* __restrict__ W_ea, const float* __restrict__ b_ea,
    u16* __restrict__ out, float2* __restrict__ na01,
    float* __restrict__ dp, float* __restrict__ dq, int N) {
  int v = blockIdx.x * 4 + (threadIdx.x >> 6);
  if (v >= N) return;
  int lane = threadIdx.x & 63;
  int g = lane >> 4, li = lane & 15;
  const uint4* T = (const uint4*)t;
  float dv = dinv[v];
  float acc[8] = {0.f, 0.f, 0.f, 0.f, 0.f, 0.f, 0.f, 0.f};
  if (g == 0) {
    uint4 u = T[(size_t)v * 16 + li];
    float w0 = dv * dv;
    ACC8(acc, u, w0)
  }
  int s0 = off[v], s1 = off[v + 1];
  for (int s = s0; s < s1; s += 32) {
    int ix[8]; float wv[8];
#pragma unroll
    for (int u = 0; u < 8; u++) {
      int e = s + g + u * 4;
      bool ok = e < s1;
      int e2 = ok ? e : s0;
      ix[u] = csr_src[e2];
      wv[u] = ok ? wseg[e2] : 0.f;
    }
    uint4 uu[8];
#pragma unroll
    for (int u = 0; u < 8; u++) uu[u] = T[(size_t)ix[u] * 16 + li];
#pragma unroll
    for (int u = 0; u < 8; u++) { float w = wv[u] * dv; ACC8(acc, uu[u], w) }
  }
#pragma unroll
  for (int j = 0; j < 8; j++) {
    acc[j] += __shfl_xor(acc[j], 16);
    acc[j] += __shfl_xor(acc[j], 32);
  }
  // all lanes now hold full sums; compute output row (bias+relu) in all lanes
  float o[8];
#pragma unroll
  for (int j = 0; j < 8; j++) o[j] = fmaxf(acc[j] + bias[li * 8 + j], 0.f);
  if (g == 0) {
    uint4 w4;
    w4.x = pack2(o[0], o[1]); w4.y = pack2(o[2], o[3]);
    w4.z = pack2(o[4], o[5]); w4.w = pack2(o[6], o[7]);
    ((uint4*)out)[(size_t)v * 16 + li] = w4;
  }
  // 6 dot products with W_na / W_ea (p and q halves)
  float d0 = 0, d1 = 0, d2 = 0, d3 = 0, d4 = 0, d5 = 0;
#pragma unroll
  for (int j = 0; j < 8; j++) {
    int k = li * 8 + j;
    float hv = o[j];
    d0 += hv * W_na[k * 2];       d1 += hv * W_na[k * 2 + 1];
    d2 += hv * W_ea[k * 2];       d3 += hv * W_ea[k * 2 + 1];
    d4 += hv * W_ea[(H + k) * 2]; d5 += hv * W_ea[(H + k) * 2 + 1];
  }
#pragma unroll
  for (int m = 1; m < 16; m <<= 1) {
    d0 += __shfl_xor(d0, m); d1 += __shfl_xor(d1, m);
    d2 += __shfl_xor(d2, m); d3 += __shfl_xor(d3, m);
    d4 += __shfl_xor(d4, m); d5 += __shfl_xor(d5, m);
  }
  if (g == 0 && li == 0) {
    float sa0 = d0 + b_na[0], sa1 = d1 + b_na[1];
    float mm = fmaxf(sa0, sa1);
    float e0 = expf(sa0 - mm), e1 = expf(sa1 - mm);
    float inv = 1.f / (e0 + e1);
    na01[v] = make_float2(e0 * inv, e1 * inv);
    dp[v] = (d2 + b_ea[0]) - (d3 + b_ea[1]);
    dq[v] = d4 - d5;
  }
}

// dual aggregation; per-source coefficients pre-packed in f4
__global__ __launch_bounds__(256) void aggdual_kernel(
    const u16* __restrict__ h, const int* __restrict__ csr_src,
    const float* __restrict__ att0s, const float4* __restrict__ f4,
    const int* __restrict__ off,
    u16* __restrict__ gc, u16* __restrict__ go,
    float* __restrict__ sumw_c, float* __restrict__ sumw_o, int N) {
  int v = blockIdx.x * 4 + (threadIdx.x >> 6);
  if (v >= N) return;
  int lane = threadIdx.x & 63;
  int g = lane >> 4, li = lane & 15;
  const uint4* T = (const uint4*)h;
  float4 fv = f4[v];
  float dvc = fv.x, dvo = fv.y;
  float ac[8] = {0.f, 0.f, 0.f, 0.f, 0.f, 0.f, 0.f, 0.f};
  float ao[8] = {0.f, 0.f, 0.f, 0.f, 0.f, 0.f, 0.f, 0.f};
  float swc = 0.f, swo = 0.f;
  if (g == 0) {
    uint4 u = T[(size_t)v * 16 + li];
    float wch = dvc * fv.z, woh = dvo * fv.w;
    ACC8(ac, u, wch)
    ACC8(ao, u, woh)
  }
  int s0 = off[v], s1 = off[v + 1];
  for (int s = s0; s < s1; s += 16) {
    int ix[4]; float a0v[4];
#pragma unroll
    for (int u = 0; u < 4; u++) {
      int e = s + g + u * 4;
      bool ok = e < s1;
      int e2 = ok ? e : s0;
      ix[u] = csr_src[e2];
      a0v[u] = ok ? att0s[e2] : -1.f;  // sentinel: both weights zero
    }
    uint4 uu[4];
    float4 fs[4];
#pragma unroll
    for (int u = 0; u < 4; u++) {
      int sidx = ix[u];
      uu[u] = T[(size_t)sidx * 16 + li];
      fs[u] = f4[sidx];
    }
#pragma unroll
    for (int u = 0; u < 4; u++) {
      float a0 = a0v[u];
      bool ok = a0 >= 0.f;
      float a1 = ok ? (1.0f - a0) : 0.f;
      if (!ok) a0 = 0.f;
      float wc = a0 * fs[u].z * dvc; ACC8(ac, uu[u], wc)
      float wo = a1 * fs[u].w * dvo; ACC8(ao, uu[u], wo)
      swc += a0 * fs[u].x; swo += a1 * fs[u].y;
    }
  }
#pragma unroll
  for (int j = 0; j < 8; j++) {
    ac[j] += __shfl_xor(ac[j], 16); ac[j] += __shfl_xor(ac[j], 32);
    ao[j] += __shfl_xor(ao[j], 16); ao[j] += __shfl_xor(ao[j], 32);
  }
  swc += __shfl_xor(swc, 16); swc += __shfl_xor(swc, 32);
  swo += __shfl_xor(swo, 16); swo += __shfl_xor(swo, 32);
  if (g == 0) {
    uint4 wc4, wo4;
    wc4.x = pack2(ac[0], ac[1]); wc4.y = pack2(ac[2], ac[3]);
    wc4.z = pack2(ac[4], ac[5]); wc4.w = pack2(ac[6], ac[7]);
    wo4.x = pack2(ao[0], ao[1]); wo4.y = pack2(ao[2], ao[3]);
    wo4.z = pack2(ao[4], ao[5]); wo4.w = pack2(ao[6], ao[7]);
    ((uint4*)gc)[(size_t)v * 16 + li] = wc4;
    ((uint4*)go)[(size_t)v * 16 + li] = wo4;
    if (li == 0) {
      sumw_c[v] = dvc * swc + dvc * dvc;
      sumw_o[v] = dvo * swo + dvo * dvo;
    }
  }
}

// ================= fc2 x3: [N,128]@[128,10] + log_softmax ====================
__global__ __launch_bounds__(256) void fc2x3_kernel(
    const u16* __restrict__ z0, const u16* __restrict__ z1, const u16* __restrict__ z2,
    const float* __restrict__ W2f, const float* __restrict__ c2f,
    float* __restrict__ outp, int N, int gN) {
  int j = blockIdx.x / gN, blk = blockIdx.x % gN;
  int n = blk * 256 + threadIdx.x;
  if (n >= N) return;
  const u16* z = (j == 0) ? z0 : (j == 1) ? z1 : z2;
  const float* W2 = W2f + (size_t)j * H * NCLS;
  const float* c2 = c2f + j * 16;
  float* op = outp + (size_t)j * N * NCLS;
  float acc[NCLS];
#pragma unroll
  for (int c = 0; c < NCLS; c++) acc[c] = c2[c];
  const uint2* zr = (const uint2*)(z + (size_t)n * H);
  for (int c4 = 0; c4 < 32; c4++) {
    uint2 u = zr[c4];
    float v[4] = {bflo(u.x), bfhi(u.x), bflo(u.y), bfhi(u.y)};
    int k = c4 * 4;
#pragma unroll
    for (int jj = 0; jj < 4; jj++)
#pragma unroll
      for (int c = 0; c < NCLS; c++) acc[c] += v[jj] * W2[(k + jj) * NCLS + c];
  }
  float m = acc[0];
#pragma unroll
  for (int c = 1; c < NCLS; c++) m = fmaxf(m, acc[c]);
  float s = 0.f;
#pragma unroll
  for (int c = 0; c < NCLS; c++) s += expf(acc[c] - m);
  float lse = logf(s) + m;
#pragma unroll
  for (int c = 0; c < NCLS; c++) op[(size_t)n * NCLS + c] = acc[c] - lse;
}

// =============================================================================
extern "C" void kernel_launch(void* const* d_in, const int* in_sizes, int n_in,
                              void* d_out, int out_size, void* d_ws, size_t ws_size,
                              hipStream_t stream) {
  const int N = in_sizes[0] / H;
  const int E = in_sizes[1] / 2;
  const float* x = (const float*)d_in[0];
  const int* ei = (const int*)d_in[1];
  const int* row = ei;
  const int* col = ei + E;
  const int* perm = (const int*)d_in[2];
  const float* W_feat = (const float*)d_in[3];
  const float* b_feat = (const float*)d_in[4];
  const float* W_convs = (const float*)d_in[5];
  const float* b_convs = (const float*)d_in[6];
  const float* W_ea = (const float*)d_in[7];
  const float* b_ea = (const float*)d_in[8];
  const float* W_na = (const float*)d_in[9];
  const float* b_na = (const float*)d_in[10];
  const float* W_ctx = (const float*)d_in[11];
  const float* b_ctx = (const float*)d_in[12];
  const float* W_obj = (const float*)d_in[13];
  const float* b_obj = (const float*)d_in[14];
  const float* W_fc1 = (const float*)d_in[15];
  const float* b_fc1 = (const float*)d_in[16];
  const float* W_fc2 = (const float*)d_in[17];
  const float* b_fc2 = (const float*)d_in[18];
  float* out = (float*)d_out;

  const int gG = (N + 63) / 64;
  const int gN = (N + 255) / 256;
  const int gE = (E + 255) / 256;
  const int SB = (N + 255) / 256;
  const int n4 = N * 32;
  const int gAgg = (N + 3) / 4;
  const float invN = 1.0f / (float)N;

  // ---------- workspace carve ----------
  char* base = (char*)d_ws;
  size_t off_b = 0;
  auto alloc = [&](size_t bytes) -> void* {
    void* p = base + off_b;
    off_b = (off_b + bytes + 255) & ~(size_t)255;
    return p;
  };
  size_t NB2 = (size_t)N * H * sizeof(u16);
  u16* bufA = (u16*)alloc(NB2);  // h chain; hco; z2
  u16* bufB = (u16*)alloc(NB2);  // conv t temp
  u16* bufC = (u16*)alloc(NB2);  // gc -> xc -> z0
  u16* bufD = (u16*)alloc(NB2);  // go -> xo -> z1
  int* cnt_in = (int*)alloc(2 * (size_t)N * 4);  // cnt_in, cnt_out (one memset)
  int* cnt_out = cnt_in + N;
  float* stpX = (float*)alloc((size_t)CS_BLOCKS * 256 * 4);
  float* stpG = (float*)alloc(3 * (size_t)gG * 256 * 4);
  float* stpPre = (float*)alloc((size_t)CS_BLOCKS * 512 * 4);
  float* stpCO = (float*)alloc((size_t)CS_BLOCKS * 256 * 4);
  int* off_in = (int*)alloc(((size_t)N + 1) * 4);
  int* off_out = (int*)alloc(((size_t)N + 1) * 4);
  float* dinv = (float*)alloc((size_t)N * 4);
  float* sumw_c = (float*)alloc((size_t)N * 4);
  float* sumw_o = (float*)alloc((size_t)N * 4);
  float2* na01 = (float2*)alloc((size_t)N * 8);
  float* dp = (float*)alloc((size_t)N * 4);
  float* dq = (float*)alloc((size_t)N * 4);
  float4* f4 = (float4*)alloc((size_t)N * 16);
  int* partial_in = (int*)alloc(256 * 4);
  int* partial_out = (int*)alloc(256 * 4);
  int* blockoff_in = (int*)alloc(256 * 4);
  int* blockoff_out = (int*)alloc(256 * 4);
  u16* WtA = (u16*)alloc((size_t)H * H * 2);
  u16* WtB = (u16*)alloc((size_t)H * H * 2);
  u16* Wt2 = (u16*)alloc(2 * (size_t)H * H * 2);
  u16* Wt3 = (u16*)alloc(3 * (size_t)H * H * 2);
  float* cfA = (float*)alloc(H * 4);
  float* cfB = (float*)alloc(H * 4);
  float* cf2 = (float*)alloc(2 * H * 4);
  float* cf3 = (float*)alloc(3 * H * 4);
  float* W2f = (float*)alloc(3 * (size_t)H * NCLS * 4);
  float* c2f = (float*)alloc(3 * 16 * 4);
  int* rank_in = (int*)alloc((size_t)E * 4);
  int* rank_out = (int*)alloc((size_t)E * 4);
  int* csr_src = (int*)alloc((size_t)E * 4);
  int* slot_in = (int*)alloc((size_t)E * 4);
  int* sout = (int*)alloc((size_t)E * 4);
  float* att0s = (float*)alloc((size_t)E * 4);
  float* att_r = (float*)alloc((size_t)E * 4);
  float* wn = (float*)alloc((size_t)E * 4);

  // 1. zero histograms
  hipMemsetAsync(cnt_in, 0, 2 * (size_t)N * 4, stream);

  // 2. hist(+ranks) || xstats
  hist_xstats_kernel<<<gE + CS_BLOCKS, 256, 0, stream>>>(
      row, col, E, cnt_in, cnt_out, rank_in, rank_out, gE, x, n4, stpX);
  // 3. scanA(both + dinv) || fold(feat)
  scanA_fold_kernel<<<SB + 64, 256, 0, stream>>>(
      cnt_in, cnt_out, N, partial_in, partial_out, dinv, SB, stpX, W_feat, b_feat,
      invN, WtA, cfA);
  // 4. scanB(both) || gemm_x
  scanB_gemmx_kernel<<<1 + gG, 256, 0, stream>>>(
      partial_in, partial_out, SB, blockoff_in, blockoff_out, x, WtA, cfA, bufA, N, stpG);
  // 5. scanC(both) || fold(conv0)
  scanC_fold_kernel<<<SB + 64, 256, 0, stream>>>(
      cnt_in, cnt_out, N, blockoff_in, blockoff_out, off_in, off_out, E, SB,
      stpG, gG, W_convs, invN, WtB, cfB);
  // 6. place(non-atomic) || gemm(conv0: bufA -> bufB)
  place_gemm_kernel<<<gE + gG, 256, 0, stream>>>(
      row, col, E, rank_in, rank_out, off_in, off_out, dinv, csr_src, slot_in, sout,
      wn, gE, bufA, WtB, cfB, bufB, N);
  // 7. agg(conv0) -> h1 in bufA
  agg_kernel<<<gAgg, 256, 0, stream>>>(bufB, csr_src, wn, off_in, dinv, b_convs, bufA, N);

  // conv 1 (plain agg)
  colstats_kernel<<<CS_BLOCKS, 256, 0, stream>>>(bufA, N, stpX);
  fold256_kernel<<<64, 256, 0, stream>>>(stpX, CS_BLOCKS, W_convs + (size_t)1 * H * H,
                                         nullptr, invN, WtB, cfB);
  gemm_kernel<<<gG, 256, 0, stream>>>(bufA, WtB, cfB, bufB, N, 0);
  agg_kernel<<<gAgg, 256, 0, stream>>>(bufB, csr_src, wn, off_in, dinv,
                                       b_convs + (size_t)1 * H, bufA, N);

  // conv 2 (agg fused with node/edge-attention factor computation)
  colstats_kernel<<<CS_BLOCKS, 256, 0, stream>>>(bufA, N, stpX);
  fold256_kernel<<<64, 256, 0, stream>>>(stpX, CS_BLOCKS, W_convs + (size_t)2 * H * H,
                                         nullptr, invN, WtB, cfB);
  gemm_kernel<<<gG, 256, 0, stream>>>(bufA, WtB, cfB, bufB, N, 0);
  agg_natt_kernel<<<gAgg, 256, 0, stream>>>(bufB, csr_src, wn, off_in, dinv,
                                            b_convs + (size_t)2 * H, W_na, b_na,
                                            W_ea, b_ea, bufA, na01, dp, dq, N);

  // attention
  eatt_xpre_kernel<<<gE + CS_BLOCKS, 256, 0, stream>>>(
      row, col, E, dp, dq, slot_in, sout, att0s, att_r, gE,
      bufA, na01, n4, stpPre);
  degsum_fold2_kernel<<<gN + 128, 256, 0, stream>>>(
      att_r, off_out, na01, f4, N, gN, stpPre, W_ctx, W_obj, invN, Wt2, cf2);
  aggdual_kernel<<<gAgg, 256, 0, stream>>>(bufA, csr_src, att0s, f4,
                                           off_in, bufC, bufD, sumw_c, sumw_o, N);
  gemm2sw_kernel<<<2 * gG, 256, 0, stream>>>(bufC, bufD, Wt2, cf2, b_ctx, b_obj,
                                             sumw_c, sumw_o, N, gG, stpG);
  // xc=bufC, xo=bufD; stats in stpG[0..2*gG)

  // h_co = xc[perm] + xo (+stats) || fold3 heads 0,1
  permadd_fold31_kernel<<<CS_BLOCKS + 128, 256, 0, stream>>>(
      bufC, bufD, perm, bufA, n4, stpCO, stpG, gG, W_fc1, b_fc1, invN, Wt3, cf3);
  // fold3 head 2 (stats from permadd)
  fold256_kernel<<<64, 256, 0, stream>>>(stpCO, CS_BLOCKS, W_fc1 + 2 * (size_t)H * H,
                                         b_fc1 + 2 * H, invN, Wt3 + 2 * (size_t)H * H,
                                         cf3 + 2 * H);
  gemm3_kernel<<<3 * gG, 256, 0, stream>>>(bufC, bufD, bufA, Wt3, cf3, N, gG, stpG);
  fold10x3_kernel<<<3 * NCLS, 128, 0, stream>>>(stpG, gG, W_fc2, b_fc2, invN, W2f, c2f);
  fc2x3_kernel<<<3 * gN, 256, 0, stream>>>(bufC, bufD, bufA, W2f, c2f, out, N, gN);
}

// Round 7
// 831.178 us; speedup vs baseline: 1.0333x; 1.0127x over previous
//
#include <hip/hip_runtime.h>
#include <math.h>

#define H 128
#define NCLS 10
#define EPS 1e-5f
#define BN_BETA 1e-4f
#define CS_BLOCKS 256

typedef unsigned short u16;
typedef unsigned int u32;
typedef __attribute__((ext_vector_type(8))) short short8;
typedef __attribute__((ext_vector_type(4))) float floatx4;

// ---- bf16 helpers (bit ops; RNE) ----
__device__ inline float bflo(u32 u) { union { u32 i; float f; } a; a.i = u << 16; return a.f; }
__device__ inline float bfhi(u32 u) { union { u32 i; float f; } a; a.i = u & 0xffff0000u; return a.f; }
__device__ inline u16 f2bf(float f) {
  union { float f; u32 i; } v; v.f = f;
  return (u16)((v.i + 0x7fff + ((v.i >> 16) & 1)) >> 16);
}
__device__ inline u32 pack2(float a, float b) { return (u32)f2bf(a) | ((u32)f2bf(b) << 16); }

// ---- latency-tolerant partial-row reduction: 8 independent streams ----------
__device__ inline void reduce_partials(const float* __restrict__ P, int nb, int stride,
                                       int off0, int f, float* su_out, float* sq_out) {
  float su[8] = {0, 0, 0, 0, 0, 0, 0, 0}, sq[8] = {0, 0, 0, 0, 0, 0, 0, 0};
  int b = 0;
  for (; b + 8 <= nb; b += 8) {
#pragma unroll
    for (int u = 0; u < 8; u++) {
      const float* p = P + (size_t)(b + u) * stride + off0;
      su[u] += p[f];
      sq[u] += p[128 + f];
    }
  }
  for (; b < nb; b++) {
    const float* p = P + (size_t)b * stride + off0;
    su[0] += p[f];
    sq[0] += p[128 + f];
  }
  *su_out = ((su[0] + su[1]) + (su[2] + su[3])) + ((su[4] + su[5]) + (su[6] + su[7]));
  *sq_out = ((sq[0] + sq[1]) + (sq[2] + sq[3])) + ((sq[4] + sq[5]) + (sq[6] + sq[7]));
}

// ---- fold body for 256 threads: 2 output columns per block -----------------
__device__ inline void fold256_body(const float* P, int nb, int stride, int off0,
                                    const float* W, const float* bias, float invN,
                                    int kp, u16* Wt, float* cf) {
  int f = threadIdx.x & 127;
  int half = threadIdx.x >> 7;
  int k = kp * 2 + half;
  float su, sq;
  reduce_partials(P, nb, stride, off0, f, &su, &sq);
  float mu = su * invN;
  float var = sq * invN - mu * mu;
  float s = 1.0f / sqrtf(fmaxf(var, 0.f) + EPS);
  float w = W[(size_t)f * H + k];
  Wt[(size_t)k * H + f] = f2bf(s * w);
  __shared__ float red[2][128];
  red[half][f] = (BN_BETA - mu * s) * w;
  __syncthreads();
  for (int o = 64; o > 0; o >>= 1) {
    if (f < o) red[half][f] += red[half][f + o];
    __syncthreads();
  }
  if (f == 0) cf[k] = red[half][0] + (bias ? bias[k] : 0.f);
}

// ================= small device bodies ======================================
// hist with rank capture: rank = old count (free slot assignment)
__device__ inline void hist_body(const int* __restrict__ row, const int* __restrict__ col,
                                 int E, int* cnt_in, int* cnt_out,
                                 int* rank_in, int* rank_out, int blk) {
  int e = blk * 256 + threadIdx.x;
  if (e < E) {
    rank_in[e] = atomicAdd(&cnt_in[col[e]], 1);
    rank_out[e] = atomicAdd(&cnt_out[row[e]], 1);
  }
}

__device__ inline void xstats_body(const float* __restrict__ x, int n4,
                                   float* __restrict__ stp, int blk) {
  int tid = threadIdx.x;
  int lane = tid & 63, wave = tid >> 6;
  float s[4] = {0, 0, 0, 0}, q[4] = {0, 0, 0, 0};
  int step = CS_BLOCKS * 256;
  for (int i = blk * 256 + tid; i < n4; i += step) {
    float4 v = ((const float4*)x)[i];
    s[0] += v.x; q[0] += v.x * v.x; s[1] += v.y; q[1] += v.y * v.y;
    s[2] += v.z; q[2] += v.z * v.z; s[3] += v.w; q[3] += v.w * v.w;
  }
#pragma unroll
  for (int k = 0; k < 4; k++) { s[k] += __shfl_xor(s[k], 32); q[k] += __shfl_xor(q[k], 32); }
  __shared__ float smx[4][256];
  int col = (lane & 31) * 4;
  if (lane < 32) {
#pragma unroll
    for (int k = 0; k < 4; k++) { smx[wave][col + k] = s[k]; smx[wave][128 + col + k] = q[k]; }
  }
  __syncthreads();
  stp[(size_t)blk * 256 + tid] = smx[0][tid] + smx[1][tid] + smx[2][tid] + smx[3][tid];
}

// scanA: block sums of cnt_in and cnt_out + dinv from out-degree
__device__ inline void scanA_body(const int* cnt_in, const int* cnt_out, int N,
                                  int* partial_in, int* partial_out, float* dinv, int blk) {
  int i = blk * 256 + threadIdx.x;
  int vo = (i < N) ? cnt_out[i] : 0;
  if (i < N) dinv[i] = 1.0f / sqrtf((float)vo + 1.0f);
  __shared__ int sdA[256];
  sdA[threadIdx.x] = (i < N) ? cnt_in[i] : 0;
  __syncthreads();
  for (int o = 128; o > 0; o >>= 1) {
    if (threadIdx.x < o) sdA[threadIdx.x] += sdA[threadIdx.x + o];
    __syncthreads();
  }
  if (threadIdx.x == 0) partial_in[blk] = sdA[0];
  __syncthreads();
  sdA[threadIdx.x] = vo;
  __syncthreads();
  for (int o = 128; o > 0; o >>= 1) {
    if (threadIdx.x < o) sdA[threadIdx.x] += sdA[threadIdx.x + o];
    __syncthreads();
  }
  if (threadIdx.x == 0) partial_out[blk] = sdA[0];
}

__device__ inline void scanB1(const int* partial, int nb, int* blockoff) {
  __shared__ int sdB[256];
  int t = threadIdx.x;
  int v = (t < nb) ? partial[t] : 0;
  sdB[t] = v;
  __syncthreads();
  for (int o = 1; o < 256; o <<= 1) {
    int x = (t >= o) ? sdB[t - o] : 0;
    __syncthreads();
    sdB[t] += x;
    __syncthreads();
  }
  blockoff[t] = sdB[t] - v;
  __syncthreads();
}

__device__ inline void scanC1(const int* cnt, int N, const int* blockoff,
                              int* off, int E, int blk) {
  __shared__ int sdC[256];
  int t = threadIdx.x;
  int i = blk * 256 + t;
  int v = (i < N) ? cnt[i] : 0;
  sdC[t] = v;
  __syncthreads();
  for (int o = 1; o < 256; o <<= 1) {
    int x = (t >= o) ? sdC[t - o] : 0;
    __syncthreads();
    sdC[t] += x;
    __syncthreads();
  }
  if (i < N) off[i] = blockoff[blk] + sdC[t] - v;
  if (i == 0) off[N] = E;
  __syncthreads();
}

// non-atomic place via precomputed ranks
__device__ inline void place_body(const int* row, const int* col, int E,
                                  const int* rank_in, const int* rank_out,
                                  const int* off_in, const int* off_out,
                                  const float* dinv, int* csr_src, int* slot_in,
                                  int* sout, float* wn, int blk) {
  int e = blk * 256 + threadIdx.x;
  if (e < E) {
    int c = col[e], r = row[e];
    int si = off_in[c] + rank_in[e];
    csr_src[si] = r;
    slot_in[e] = si;
    wn[si] = dinv[r];
    sout[e] = off_out[r] + rank_out[e];
  }
}

// eatt via dp/dq scalars (b_ea folded into dp): half the random gather bytes
__device__ inline void eatt_body(const int* row, const int* col, int E,
                                 const float* dp, const float* dq,
                                 const int* slot_in, const int* sout,
                                 float* att0s, float* att_r, int blk) {
  int e = blk * 256 + threadIdx.x;
  if (e >= E) return;
  float a0 = 1.0f / (1.0f + expf(-(dp[row[e]] + dq[col[e]])));
  att0s[slot_in[e]] = a0;
  att_r[sout[e]] = a0;
}

// degsum + per-node coefficient pack: f4 = (dvc, dvo, dvc*na.x, dvo*na.y)
__device__ inline void degsum_f4_body(const float* att_r, const int* off_out,
                                      const float2* na01, float4* f4, int N, int blk) {
  int v = blk * 256 + threadIdx.x;
  if (v >= N) return;
  int s0 = off_out[v], s1 = off_out[v + 1];
  float s = 0.f;
  for (int i = s0; i < s1; i++) s += att_r[i];
  float dvc = 1.0f / sqrtf(s + 1.0f);
  float dvo = 1.0f / sqrtf((float)(s1 - s0) - s + 1.0f);
  float2 na = na01[v];
  f4[v] = make_float4(dvc, dvo, dvc * na.x, dvo * na.y);
}

__device__ inline void xprestats_body(const u16* __restrict__ h,
                                      const float2* __restrict__ na01, int n4,
                                      float* __restrict__ stp, int blk) {
  int tid = threadIdx.x;
  int lane = tid & 63, wave = tid >> 6;
  float sc[4] = {0, 0, 0, 0}, qc[4] = {0, 0, 0, 0};
  float so[4] = {0, 0, 0, 0}, qo[4] = {0, 0, 0, 0};
  int step = CS_BLOCKS * 256;
  for (int i = blk * 256 + tid; i < n4; i += step) {
    int n = i >> 5;
    uint2 u = ((const uint2*)h)[i];
    float v0 = bflo(u.x), v1 = bfhi(u.x), v2 = bflo(u.y), v3 = bfhi(u.y);
    float2 ab = na01[n];
    float a = ab.x, b = ab.y;
    float c0 = v0 * a, c1 = v1 * a, c2 = v2 * a, c3 = v3 * a;
    float o0 = v0 * b, o1 = v1 * b, o2 = v2 * b, o3 = v3 * b;
    sc[0] += c0; qc[0] += c0 * c0; sc[1] += c1; qc[1] += c1 * c1;
    sc[2] += c2; qc[2] += c2 * c2; sc[3] += c3; qc[3] += c3 * c3;
    so[0] += o0; qo[0] += o0 * o0; so[1] += o1; qo[1] += o1 * o1;
    so[2] += o2; qo[2] += o2 * o2; so[3] += o3; qo[3] += o3 * o3;
  }
#pragma unroll
  for (int k = 0; k < 4; k++) {
    sc[k] += __shfl_xor(sc[k], 32); qc[k] += __shfl_xor(qc[k], 32);
    so[k] += __shfl_xor(so[k], 32); qo[k] += __shfl_xor(qo[k], 32);
  }
  __shared__ float smp[4][512];
  int col = (lane & 31) * 4;
  if (lane < 32) {
#pragma unroll
    for (int k = 0; k < 4; k++) {
      smp[wave][col + k] = sc[k];
      smp[wave][128 + col + k] = qc[k];
      smp[wave][256 + col + k] = so[k];
      smp[wave][384 + col + k] = qo[k];
    }
  }
  __syncthreads();
  float r0 = smp[0][tid] + smp[1][tid] + smp[2][tid] + smp[3][tid];
  float r1 = smp[0][256 + tid] + smp[1][256 + tid] + smp[2][256 + tid] + smp[3][256 + tid];
  stp[(size_t)blk * 512 + tid] = r0;
  stp[(size_t)blk * 512 + 256 + tid] = r1;
}

// ================= bf16 MFMA GEMM core ======================================
__device__ inline void gemm_core(const u16* A, const float* Afp, const u16* Bt,
                                 const float* cf, const float* b2, const float* sumw,
                                 u16* C, int N, int relu, int blk, float* stp) {
  int tid = threadIdx.x;
  int wave = tid >> 6, lane = tid & 63;
  int l15 = lane & 15, quad = lane >> 4;
  int row0 = (blk * 4 + wave) * 16;
  if (row0 >= N && !stp) return;
  int arow = row0 + l15;
  short8 a[4];
  short8 z8 = {0, 0, 0, 0, 0, 0, 0, 0};
  if (Afp) {
#pragma unroll
    for (int k4 = 0; k4 < 4; k4++) {
      if (arow < N) {
        const float* p = Afp + (size_t)arow * H + k4 * 32 + quad * 8;
        float4 f0 = *(const float4*)p;
        float4 f1 = *(const float4*)(p + 4);
        union { short8 s8; u32 u[4]; } cv;
        cv.u[0] = pack2(f0.x, f0.y); cv.u[1] = pack2(f0.z, f0.w);
        cv.u[2] = pack2(f1.x, f1.y); cv.u[3] = pack2(f1.z, f1.w);
        a[k4] = cv.s8;
      } else a[k4] = z8;
    }
  } else {
#pragma unroll
    for (int k4 = 0; k4 < 4; k4++)
      a[k4] = (arow < N) ? *(const short8*)(A + (size_t)arow * H + k4 * 32 + quad * 8) : z8;
  }
  float srow[4];
  if (sumw) {
#pragma unroll
    for (int r = 0; r < 4; r++) {
      int row = row0 + quad * 4 + r;
      srow[r] = (row < N) ? sumw[row] : 0.f;
    }
  }
  float ps[8], pq[8];
#pragma unroll
  for (int nt = 0; nt < 8; nt++) {
    floatx4 acc = {0.f, 0.f, 0.f, 0.f};
    const u16* bp = Bt + (size_t)(nt * 16 + l15) * H + quad * 8;
#pragma unroll
    for (int k4 = 0; k4 < 4; k4++) {
      short8 b = *(const short8*)(bp + k4 * 32);
      acc = __builtin_amdgcn_mfma_f32_16x16x32_bf16(a[k4], b, acc, 0, 0, 0);
    }
    int col = nt * 16 + l15;
    float base = cf[col];
    float bb = b2 ? b2[col] : 0.f;
    float s_ = 0.f, q_ = 0.f;
#pragma unroll
    for (int r = 0; r < 4; r++) {
      int row = row0 + quad * 4 + r;
      if (row < N) {
        float v = acc[r] + (sumw ? srow[r] * base + bb : base);
        if (relu) v = fmaxf(v, 0.f);
        s_ += v; q_ += v * v;
        C[(size_t)row * H + col] = f2bf(v);
      }
    }
    ps[nt] = s_; pq[nt] = q_;
  }
  if (stp) {
    __shared__ float sred[4][256];
#pragma unroll
    for (int nt = 0; nt < 8; nt++) {
      ps[nt] += __shfl_xor(ps[nt], 16); ps[nt] += __shfl_xor(ps[nt], 32);
      pq[nt] += __shfl_xor(pq[nt], 16); pq[nt] += __shfl_xor(pq[nt], 32);
    }
    if (quad == 0) {
#pragma unroll
      for (int nt = 0; nt < 8; nt++) {
        sred[wave][nt * 16 + l15] = ps[nt];
        sred[wave][128 + nt * 16 + l15] = pq[nt];
      }
    }
    __syncthreads();
    stp[(size_t)blk * 256 + tid] =
        sred[0][tid] + sred[1][tid] + sred[2][tid] + sred[3][tid];
  }
}

// ================= merged kernels ===========================================
__global__ __launch_bounds__(256) void xstats_kernel(
    const float* x, int n4, float* stpX) {
  xstats_body(x, n4, stpX, blockIdx.x);
}

// gemm_x (dependency-free of hist) overlapped under the hist atomic wall.
// gemm blocks first so they start issuing MFMA immediately; hist blocks
// stream in behind and saturate the atomic unit.
__global__ __launch_bounds__(256) void gemmx_hist_kernel(
    const float* x, const u16* WtA, const float* cfA, u16* C, int N,
    float* stpG, int gG,
    const int* row, const int* col, int E, int* cnt_in, int* cnt_out,
    int* rank_in, int* rank_out) {
  if ((int)blockIdx.x < gG)
    gemm_core(nullptr, x, WtA, cfA, nullptr, nullptr, C, N, 1, blockIdx.x, stpG);
  else
    hist_body(row, col, E, cnt_in, cnt_out, rank_in, rank_out, blockIdx.x - gG);
}

// scanA + fold(conv0) from gemm_x stats
__global__ __launch_bounds__(256) void scanA_fold_kernel(
    const int* cnt_in, const int* cnt_out, int N, int* partial_in, int* partial_out,
    float* dinv, int SB, const float* stpG, int nbG, const float* Wc,
    float invN, u16* WtB, float* cfB) {
  if ((int)blockIdx.x < SB)
    scanA_body(cnt_in, cnt_out, N, partial_in, partial_out, dinv, blockIdx.x);
  else
    fold256_body(stpG, nbG, 256, 0, Wc, nullptr, invN, blockIdx.x - SB, WtB, cfB);
}

__global__ __launch_bounds__(256) void scanB_kernel(
    const int* partial_in, const int* partial_out, int nb,
    int* blockoff_in, int* blockoff_out) {
  scanB1(partial_in, nb, blockoff_in);
  scanB1(partial_out, nb, blockoff_out);
}

__global__ __launch_bounds__(256) void scanC_kernel(
    const int* cnt_in, const int* cnt_out, int N, const int* blockoff_in,
    const int* blockoff_out, int* off_in, int* off_out, int E) {
  scanC1(cnt_in, N, blockoff_in, off_in, E, blockIdx.x);
  scanC1(cnt_out, N, blockoff_out, off_out, E, blockIdx.x);
}

__global__ __launch_bounds__(256) void place_gemm_kernel(
    const int* row, const int* col, int E, const int* rank_in, const int* rank_out,
    const int* off_in, const int* off_out, const float* dinv, int* csr_src,
    int* slot_in, int* sout, float* wn, int gE,
    const u16* A, const u16* WtB, const float* cfB, u16* C, int N) {
  if ((int)blockIdx.x < gE)
    place_body(row, col, E, rank_in, rank_out, off_in, off_out, dinv, csr_src,
               slot_in, sout, wn, blockIdx.x);
  else
    gemm_core(A, nullptr, WtB, cfB, nullptr, nullptr, C, N, 0, blockIdx.x - gE, nullptr);
}

__global__ __launch_bounds__(256) void eatt_xpre_kernel(
    const int* row, const int* col, int E, const float* dp, const float* dq,
    const int* slot_in, const int* sout, float* att0s,
    float* att_r, int gE, const u16* h, const float2* na01, int n4, float* stpPre) {
  if ((int)blockIdx.x < gE)
    eatt_body(row, col, E, dp, dq, slot_in, sout, att0s, att_r, blockIdx.x);
  else
    xprestats_body(h, na01, n4, stpPre, blockIdx.x - gE);
}

__global__ __launch_bounds__(256) void degsum_fold2_kernel(
    const float* att_r, const int* off_out, const float2* na01, float4* f4,
    int N, int gN,
    const float* stpPre, const float* W_ctx, const float* W_obj, float invN,
    u16* Wt2, float* cf2) {
  if ((int)blockIdx.x < gN)
    degsum_f4_body(att_r, off_out, na01, f4, N, blockIdx.x);
  else {
    int b = blockIdx.x - gN;  // 0..127
    int j = b >> 6, kp = b & 63;
    fold256_body(stpPre, CS_BLOCKS, 512, j * 256, j ? W_obj : W_ctx, nullptr, invN, kp,
                 Wt2 + (size_t)j * H * H, cf2 + j * H);
  }
}

__global__ __launch_bounds__(256) void permadd_fold31_kernel(
    const u16* xc, const u16* xo, const int* perm, u16* outb, int n4, float* stpCO,
    const float* stpG, int nbG, const float* W_fc1, const float* b_fc1, float invN,
    u16* Wt3, float* cf3) {
  int tid = threadIdx.x;
  if ((int)blockIdx.x >= CS_BLOCKS) {
    int b = blockIdx.x - CS_BLOCKS;  // 0..127 -> heads 0,1
    int j = b >> 6, kp = b & 63;
    fold256_body(stpG + (size_t)j * nbG * 256, nbG, 256, 0, W_fc1 + (size_t)j * H * H,
                 b_fc1 + j * H, invN, kp, Wt3 + (size_t)j * H * H, cf3 + j * H);
    return;
  }
  int blk = blockIdx.x;
  int lane = tid & 63, wave = tid >> 6;
  float s[4] = {0, 0, 0, 0}, q[4] = {0, 0, 0, 0};
  int step = CS_BLOCKS * 256;
  for (int i = blk * 256 + tid; i < n4; i += step) {
    int n = i >> 5, k = i & 31;
    int p = perm[n];
    uint2 a = ((const uint2*)xc)[(size_t)p * 32 + k];
    uint2 b = ((const uint2*)xo)[i];
    float f0 = bflo(a.x) + bflo(b.x), f1 = bfhi(a.x) + bfhi(b.x);
    float f2 = bflo(a.y) + bflo(b.y), f3 = bfhi(a.y) + bfhi(b.y);
    ((uint2*)outb)[i] = make_uint2(pack2(f0, f1), pack2(f2, f3));
    s[0] += f0; q[0] += f0 * f0; s[1] += f1; q[1] += f1 * f1;
    s[2] += f2; q[2] += f2 * f2; s[3] += f3; q[3] += f3 * f3;
  }
#pragma unroll
  for (int k = 0; k < 4; k++) { s[k] += __shfl_xor(s[k], 32); q[k] += __shfl_xor(q[k], 32); }
  __shared__ float smq[4][256];
  int col = (lane & 31) * 4;
  if (lane < 32) {
#pragma unroll
    for (int k = 0; k < 4; k++) { smq[wave][col + k] = s[k]; smq[wave][128 + col + k] = q[k]; }
  }
  __syncthreads();
  stpCO[(size_t)blk * 256 + tid] = smq[0][tid] + smq[1][tid] + smq[2][tid] + smq[3][tid];
}

// ================= standalone kernels =======================================
__global__ __launch_bounds__(256) void fold256_kernel(
    const float* P, int nb, const float* W, const float* bias, float invN,
    u16* Wt, float* cf) {
  fold256_body(P, nb, 256, 0, W, bias, invN, blockIdx.x, Wt, cf);
}

__global__ __launch_bounds__(128) void fold10x3_kernel(
    const float* stpZ, int nb, const float* W_fc2, const float* b_fc2, float invN,
    float* W2f, float* c2f) {
  int j = blockIdx.x / NCLS, k = blockIdx.x % NCLS;
  const float* P = stpZ + (size_t)j * nb * 256;
  int f = threadIdx.x;
  float su, sq;
  reduce_partials(P, nb, 256, 0, f, &su, &sq);
  float mu = su * invN;
  float var = sq * invN - mu * mu;
  float s = 1.0f / sqrtf(fmaxf(var, 0.f) + EPS);
  float w = W_fc2[(size_t)j * H * NCLS + (size_t)f * NCLS + k];
  W2f[(size_t)j * H * NCLS + (size_t)f * NCLS + k] = s * w;
  __shared__ float red1[H];
  red1[f] = (BN_BETA - mu * s) * w;
  __syncthreads();
  for (int o = 64; o > 0; o >>= 1) {
    if (f < o) red1[f] += red1[f + o];
    __syncthreads();
  }
  if (f == 0) c2f[j * 16 + k] = red1[0] + b_fc2[j * NCLS + k];
}

__global__ __launch_bounds__(256) void gemm_kernel(
    const u16* A, const u16* Bt, const float* cf, u16* C, int N, int relu) {
  gemm_core(A, nullptr, Bt, cf, nullptr, nullptr, C, N, relu, blockIdx.x, nullptr);
}

__global__ __launch_bounds__(256) void gemm2sw_kernel(
    u16* B0, u16* B1, const u16* Wt2, const float* cf2,
    const float* b0, const float* b1, const float* sw0, const float* sw1,
    int N, int gG, float* stp) {
  int j = blockIdx.x / gG, blk = blockIdx.x % gG;
  u16* Z = j ? B1 : B0;
  gemm_core(Z, nullptr, Wt2 + (size_t)j * H * H, cf2 + j * H, j ? b1 : b0,
            j ? sw1 : sw0, Z, N, 1, blk, stp + (size_t)j * gG * 256);
}

__global__ __launch_bounds__(256) void gemm3_kernel(
    u16* Z0, u16* Z1, u16* Z2, const u16* Wt3, const float* cf3,
    int N, int gG, float* stp) {
  int j = blockIdx.x / gG, blk = blockIdx.x % gG;
  u16* Z = (j == 0) ? Z0 : (j == 1) ? Z1 : Z2;
  gemm_core(Z, nullptr, Wt3 + (size_t)j * H * H, cf3 + j * H, nullptr, nullptr,
            Z, N, 1, blk, stp + (size_t)j * gG * 256);
}

__global__ __launch_bounds__(256) void colstats_kernel(
    const u16* __restrict__ X, int N, float* __restrict__ stp) {
  int tid = threadIdx.x;
  int li = tid & 15, rg = tid >> 4;
  int wave = tid >> 6, lane = tid & 63;
  const uint4* T = (const uint4*)X;
  float s[8] = {0, 0, 0, 0, 0, 0, 0, 0}, q[8] = {0, 0, 0, 0, 0, 0, 0, 0};
  for (int r = blockIdx.x * 16 + rg; r < N; r += CS_BLOCKS * 16) {
    uint4 u = T[(size_t)r * 16 + li];
    float f[8] = {bflo(u.x), bfhi(u.x), bflo(u.y), bfhi(u.y),
                  bflo(u.z), bfhi(u.z), bflo(u.w), bfhi(u.w)};
#pragma unroll
    for (int j = 0; j < 8; j++) { s[j] += f[j]; q[j] += f[j] * f[j]; }
  }
#pragma unroll
  for (int j = 0; j < 8; j++) {
    s[j] += __shfl_xor(s[j], 16); s[j] += __shfl_xor(s[j], 32);
    q[j] += __shfl_xor(q[j], 16); q[j] += __shfl_xor(q[j], 32);
  }
  __shared__ float smc[4][256];
  if ((lane & 48) == 0) {
#pragma unroll
    for (int j = 0; j < 8; j++) {
      smc[wave][li * 8 + j] = s[j];
      smc[wave][128 + li * 8 + j] = q[j];
    }
  }
  __syncthreads();
  stp[(size_t)blockIdx.x * 256 + tid] = smc[0][tid] + smc[1][tid] + smc[2][tid] + smc[3][tid];
}

// ================= aggregation ==============================================
#define ACC8(A, U, W)                                             \
  A[0] += (W) * bflo(U.x); A[1] += (W) * bfhi(U.x);               \
  A[2] += (W) * bflo(U.y); A[3] += (W) * bfhi(U.y);               \
  A[4] += (W) * bflo(U.z); A[5] += (W) * bfhi(U.z);               \
  A[6] += (W) * bflo(U.w); A[7] += (W) * bfhi(U.w);

__global__ __launch_bounds__(256) void agg_kernel(
    const u16* __restrict__ t, const int* __restrict__ csr_src,
    const float* __restrict__ wseg, const int* __restrict__ off,
    const float* __restrict__ dinv, const float* __restrict__ bias,
    u16* __restrict__ out, int N) {
  int v = blockIdx.x * 4 + (threadIdx.x >> 6);
  if (v >= N) return;
  int lane = threadIdx.x & 63;
  int g = lane >> 4, li = lane & 15;
  const uint4* T = (const uint4*)t;
  float dv = dinv[v];
  float acc[8] = {0.f, 0.f, 0.f, 0.f, 0.f, 0.f, 0.f, 0.f};
  if (g == 0) {
    uint4 u = T[(size_t)v * 16 + li];
    float w0 = dv * dv;
    ACC8(acc, u, w0)
  }
  int s0 = off[v], s1 = off[v + 1];
  for (int s = s0; s < s1; s += 32) {
    int ix[8]; float wv[8];
#pragma unroll
    for (int u = 0; u < 8; u++) {
      int e = s + g + u * 4;
      bool ok = e < s1;
      int e2 = ok ? e : s0;
      ix[u] = csr_src[e2];
      wv[u] = ok ? wseg[e2] : 0.f;
    }
    uint4 uu[8];
#pragma unroll
    for (int u = 0; u < 8; u++) uu[u] = T[(size_t)ix[u] * 16 + li];
#pragma unroll
    for (int u = 0; u < 8; u++) { float w = wv[u] * dv; ACC8(acc, uu[u], w) }
  }
#pragma unroll
  for (int j = 0; j < 8; j++) {
    acc[j] += __shfl_xor(acc[j], 16);
    acc[j] += __shfl_xor(acc[j], 32);
  }
  if (g == 0) {
    float o[8];
#pragma unroll
    for (int j = 0; j < 8; j++) o[j] = fmaxf(acc[j] + bias[li * 8 + j], 0.f);
    uint4 w4;
    w4.x = pack2(o[0], o[1]); w4.y = pack2(o[2], o[3]);
    w4.z = pack2(o[4], o[5]); w4.w = pack2(o[6], o[7]);
    ((uint4*)out)[(size_t)v * 16 + li] = w4;
  }
}

// agg for the last conv + fused node-attention / edge-attention factors.
__global__ __launch_bounds__(256) void agg_natt_kernel(
    const u16* __restrict__ t, const int* __restrict__ csr_src,
    const float* __restrict__ wseg, const int* __restrict__ off,
    const float* __restrict__ dinv, const float* __restrict__ bias,
    const float* __restrict__ W_na, const float* __restrict__ b_na,
    const float* __restrict__ W_ea, const float* __restrict__ b_ea,
    u16* __restrict__ out, float2* __restrict__ na01,
    float* __restrict__ dp, float* __restrict__ dq, int N) {
  int v = blockIdx.x * 4 + (threadIdx.x >> 6);
  if (v >= N) return;
  int lane = threadIdx.x & 63;
  int g = lane >> 4, li = lane & 15;
  const uint4* T = (const uint4*)t;
  float dv = dinv[v];
  float acc[8] = {0.f, 0.f, 0.f, 0.f, 0.f, 0.f, 0.f, 0.f};
  if (g == 0) {
    uint4 u = T[(size_t)v * 16 + li];
    float w0 = dv * dv;
    ACC8(acc, u, w0)
  }
  int s0 = off[v], s1 = off[v + 1];
  for (int s = s0; s < s1; s += 32) {
    int ix[8]; float wv[8];
#pragma unroll
    for (int u = 0; u < 8; u++) {
      int e = s + g + u * 4;
      bool ok = e < s1;
      int e2 = ok ? e : s0;
      ix[u] = csr_src[e2];
      wv[u] = ok ? wseg[e2] : 0.f;
    }
    uint4 uu[8];
#pragma unroll
    for (int u = 0; u < 8; u++) uu[u] = T[(size_t)ix[u] * 16 + li];
#pragma unroll
    for (int u = 0; u < 8; u++) { float w = wv[u] * dv; ACC8(acc, uu[u], w) }
  }
#pragma unroll
  for (int j = 0; j < 8; j++) {
    acc[j] += __shfl_xor(acc[j], 16);
    acc[j] += __shfl_xor(acc[j], 32);
  }
  // all lanes now hold full sums; compute output row (bias+relu) in all lanes
  float o[8];
#pragma unroll
  for (int j = 0; j < 8; j++) o[j] = fmaxf(acc[j] + bias[li * 8 + j], 0.f);
  if (g == 0) {
    uint4 w4;
    w4.x = pack2(o[0], o[1]); w4.y = pack2(o[2], o[3]);
    w4.z = pack2(o[4], o[5]); w4.w = pack2(o[6], o[7]);
    ((uint4*)out)[(size_t)v * 16 + li] = w4;
  }
  // 6 dot products with W_na / W_ea (p and q halves)
  float d0 = 0, d1 = 0, d2 = 0, d3 = 0, d4 = 0, d5 = 0;
#pragma unroll
  for (int j = 0; j < 8; j++) {
    int k = li * 8 + j;
    float hv = o[j];
    d0 += hv * W_na[k * 2];       d1 += hv * W_na[k * 2 + 1];
    d2 += hv * W_ea[k * 2];       d3 += hv * W_ea[k * 2 + 1];
    d4 += hv * W_ea[(H + k) * 2]; d5 += hv * W_ea[(H + k) * 2 + 1];
  }
#pragma unroll
  for (int m = 1; m < 16; m <<= 1) {
    d0 += __shfl_xor(d0, m); d1 += __shfl_xor(d1, m);
    d2 += __shfl_xor(d2, m); d3 += __shfl_xor(d3, m);
    d4 += __shfl_xor(d4, m); d5 += __shfl_xor(d5, m);
  }
  if (g == 0 && li == 0) {
    float sa0 = d0 + b_na[0], sa1 = d1 + b_na[1];
    float mm = fmaxf(sa0, sa1);
    float e0 = expf(sa0 - mm), e1 = expf(sa1 - mm);
    float inv = 1.f / (e0 + e1);
    na01[v] = make_float2(e0 * inv, e1 * inv);
    dp[v] = (d2 + b_ea[0]) - (d3 + b_ea[1]);
    dq[v] = d4 - d5;
  }
}

// dual aggregation; per-source coefficients pre-packed in f4
__global__ __launch_bounds__(256) void aggdual_kernel(
    const u16* __restrict__ h, const int* __restrict__ csr_src,
    const float* __restrict__ att0s, const float4* __restrict__ f4,
    const int* __restrict__ off,
    u16* __restrict__ gc, u16* __restrict__ go,
    float* __restrict__ sumw_c, float* __restrict__ sumw_o, int N) {
  int v = blockIdx.x * 4 + (threadIdx.x >> 6);
  if (v >= N) return;
  int lane = threadIdx.x & 63;
  int g = lane >> 4, li = lane & 15;
  const uint4* T = (const uint4*)h;
  float4 fv = f4[v];
  float dvc = fv.x, dvo = fv.y;
  float ac[8] = {0.f, 0.f, 0.f, 0.f, 0.f, 0.f, 0.f, 0.f};
  float ao[8] = {0.f, 0.f, 0.f, 0.f, 0.f, 0.f, 0.f, 0.f};
  float swc = 0.f, swo = 0.f;
  if (g == 0) {
    uint4 u = T[(size_t)v * 16 + li];
    float wch = dvc * fv.z, woh = dvo * fv.w;
    ACC8(ac, u, wch)
    ACC8(ao, u, woh)
  }
  int s0 = off[v], s1 = off[v + 1];
  for (int s = s0; s < s1; s += 16) {
    int ix[4]; float a0v[4];
#pragma unroll
    for (int u = 0; u < 4; u++) {
      int e = s + g + u * 4;
      bool ok = e < s1;
      int e2 = ok ? e : s0;
      ix[u] = csr_src[e2];
      a0v[u] = ok ? att0s[e2] : -1.f;  // sentinel: both weights zero
    }
    uint4 uu[4];
    float4 fs[4];
#pragma unroll
    for (int u = 0; u < 4; u++) {
      int sidx = ix[u];
      uu[u] = T[(size_t)sidx * 16 + li];
      fs[u] = f4[sidx];
    }
#pragma unroll
    for (int u = 0; u < 4; u++) {
      float a0 = a0v[u];
      bool ok = a0 >= 0.f;
      float a1 = ok ? (1.0f - a0) : 0.f;
      if (!ok) a0 = 0.f;
      float wc = a0 * fs[u].z * dvc; ACC8(ac, uu[u], wc)
      float wo = a1 * fs[u].w * dvo; ACC8(ao, uu[u], wo)
      swc += a0 * fs[u].x; swo += a1 * fs[u].y;
    }
  }
#pragma unroll
  for (int j = 0; j < 8; j++) {
    ac[j] += __shfl_xor(ac[j], 16); ac[j] += __shfl_xor(ac[j], 32);
    ao[j] += __shfl_xor(ao[j], 16); ao[j] += __shfl_xor(ao[j], 32);
  }
  swc += __shfl_xor(swc, 16); swc += __shfl_xor(swc, 32);
  swo += __shfl_xor(swo, 16); swo += __shfl_xor(swo, 32);
  if (g == 0) {
    uint4 wc4, wo4;
    wc4.x = pack2(ac[0], ac[1]); wc4.y = pack2(ac[2], ac[3]);
    wc4.z = pack2(ac[4], ac[5]); wc4.w = pack2(ac[6], ac[7]);
    wo4.x = pack2(ao[0], ao[1]); wo4.y = pack2(ao[2], ao[3]);
    wo4.z = pack2(ao[4], ao[5]); wo4.w = pack2(ao[6], ao[7]);
    ((uint4*)gc)[(size_t)v * 16 + li] = wc4;
    ((uint4*)go)[(size_t)v * 16 + li] = wo4;
    if (li == 0) {
      sumw_c[v] = dvc * swc + dvc * dvc;
      sumw_o[v] = dvo * swo + dvo * dvo;
    }
  }
}

// ================= fc2 x3: [N,128]@[128,10] + log_softmax ====================
__global__ __launch_bounds__(256) void fc2x3_kernel(
    const u16* __restrict__ z0, const u16* __restrict__ z1, const u16* __restrict__ z2,
    const float* __restrict__ W2f, const float* __restrict__ c2f,
    float* __restrict__ outp, int N, int gN) {
  int j = blockIdx.x / gN, blk = blockIdx.x % gN;
  int n = blk * 256 + threadIdx.x;
  if (n >= N) return;
  const u16* z = (j == 0) ? z0 : (j == 1) ? z1 : z2;
  const float* W2 = W2f + (size_t)j * H * NCLS;
  const float* c2 = c2f + j * 16;
  float* op = outp + (size_t)j * N * NCLS;
  float acc[NCLS];
#pragma unroll
  for (int c = 0; c < NCLS; c++) acc[c] = c2[c];
  const uint2* zr = (const uint2*)(z + (size_t)n * H);
  for (int c4 = 0; c4 < 32; c4++) {
    uint2 u = zr[c4];
    float v[4] = {bflo(u.x), bfhi(u.x), bflo(u.y), bfhi(u.y)};
    int k = c4 * 4;
#pragma unroll
    for (int jj = 0; jj < 4; jj++)
#pragma unroll
      for (int c = 0; c < NCLS; c++) acc[c] += v[jj] * W2[(k + jj) * NCLS + c];
  }
  float m = acc[0];
#pragma unroll
  for (int c = 1; c < NCLS; c++) m = fmaxf(m, acc[c]);
  float s = 0.f;
#pragma unroll
  for (int c = 0; c < NCLS; c++) s += expf(acc[c] - m);
  float lse = logf(s) + m;
#pragma unroll
  for (int c = 0; c < NCLS; c++) op[(size_t)n * NCLS + c] = acc[c] - lse;
}

// =============================================================================
extern "C" void kernel_launch(void* const* d_in, const int* in_sizes, int n_in,
                              void* d_out, int out_size, void* d_ws, size_t ws_size,
                              hipStream_t stream) {
  const int N = in_sizes[0] / H;
  const int E = in_sizes[1] / 2;
  const float* x = (const float*)d_in[0];
  const int* ei = (const int*)d_in[1];
  const int* row = ei;
  const int* col = ei + E;
  const int* perm = (const int*)d_in[2];
  const float* W_feat = (const float*)d_in[3];
  const float* b_feat = (const float*)d_in[4];
  const float* W_convs = (const float*)d_in[5];
  const float* b_convs = (const float*)d_in[6];
  const float* W_ea = (const float*)d_in[7];
  const float* b_ea = (const float*)d_in[8];
  const float* W_na = (const float*)d_in[9];
  const float* b_na = (const float*)d_in[10];
  const float* W_ctx = (const float*)d_in[11];
  const float* b_ctx = (const float*)d_in[12];
  const float* W_obj = (const float*)d_in[13];
  const float* b_obj = (const float*)d_in[14];
  const float* W_fc1 = (const float*)d_in[15];
  const float* b_fc1 = (const float*)d_in[16];
  const float* W_fc2 = (const float*)d_in[17];
  const float* b_fc2 = (const float*)d_in[18];
  float* out = (float*)d_out;

  const int gG = (N + 63) / 64;
  const int gN = (N + 255) / 256;
  const int gE = (E + 255) / 256;
  const int SB = (N + 255) / 256;
  const int n4 = N * 32;
  const int gAgg = (N + 3) / 4;
  const float invN = 1.0f / (float)N;

  // ---------- workspace carve ----------
  char* base = (char*)d_ws;
  size_t off_b = 0;
  auto alloc = [&](size_t bytes) -> void* {
    void* p = base + off_b;
    off_b = (off_b + bytes + 255) & ~(size_t)255;
    return p;
  };
  size_t NB2 = (size_t)N * H * sizeof(u16);
  u16* bufA = (u16*)alloc(NB2);  // h chain; hco; z2
  u16* bufB = (u16*)alloc(NB2);  // conv t temp
  u16* bufC = (u16*)alloc(NB2);  // gc -> xc -> z0
  u16* bufD = (u16*)alloc(NB2);  // go -> xo -> z1
  int* cnt_in = (int*)alloc(2 * (size_t)N * 4);  // cnt_in, cnt_out (one memset)
  int* cnt_out = cnt_in + N;
  float* stpX = (float*)alloc((size_t)CS_BLOCKS * 256 * 4);
  float* stpG = (float*)alloc(3 * (size_t)gG * 256 * 4);
  float* stpPre = (float*)alloc((size_t)CS_BLOCKS * 512 * 4);
  float* stpCO = (float*)alloc((size_t)CS_BLOCKS * 256 * 4);
  int* off_in = (int*)alloc(((size_t)N + 1) * 4);
  int* off_out = (int*)alloc(((size_t)N + 1) * 4);
  float* dinv = (float*)alloc((size_t)N * 4);
  float* sumw_c = (float*)alloc((size_t)N * 4);
  float* sumw_o = (float*)alloc((size_t)N * 4);
  float2* na01 = (float2*)alloc((size_t)N * 8);
  float* dp = (float*)alloc((size_t)N * 4);
  float* dq = (float*)alloc((size_t)N * 4);
  float4* f4 = (float4*)alloc((size_t)N * 16);
  int* partial_in = (int*)alloc(256 * 4);
  int* partial_out = (int*)alloc(256 * 4);
  int* blockoff_in = (int*)alloc(256 * 4);
  int* blockoff_out = (int*)alloc(256 * 4);
  u16* WtA = (u16*)alloc((size_t)H * H * 2);
  u16* WtB = (u16*)alloc((size_t)H * H * 2);
  u16* Wt2 = (u16*)alloc(2 * (size_t)H * H * 2);
  u16* Wt3 = (u16*)alloc(3 * (size_t)H * H * 2);
  float* cfA = (float*)alloc(H * 4);
  float* cfB = (float*)alloc(H * 4);
  float* cf2 = (float*)alloc(2 * H * 4);
  float* cf3 = (float*)alloc(3 * H * 4);
  float* W2f = (float*)alloc(3 * (size_t)H * NCLS * 4);
  float* c2f = (float*)alloc(3 * 16 * 4);
  int* rank_in = (int*)alloc((size_t)E * 4);
  int* rank_out = (int*)alloc((size_t)E * 4);
  int* csr_src = (int*)alloc((size_t)E * 4);
  int* slot_in = (int*)alloc((size_t)E * 4);
  int* sout = (int*)alloc((size_t)E * 4);
  float* att0s = (float*)alloc((size_t)E * 4);
  float* att_r = (float*)alloc((size_t)E * 4);
  float* wn = (float*)alloc((size_t)E * 4);

  // 1. zero histograms
  hipMemsetAsync(cnt_in, 0, 2 * (size_t)N * 4, stream);

  // 2. xstats (small, feeds fold(feat))
  xstats_kernel<<<CS_BLOCKS, 256, 0, stream>>>(x, n4, stpX);
  // 3. fold(feat)
  fold256_kernel<<<64, 256, 0, stream>>>(stpX, CS_BLOCKS, W_feat, b_feat, invN, WtA, cfA);
  // 4. gemm_x OVERLAPPED under the hist atomic wall (disjoint resources)
  gemmx_hist_kernel<<<gG + gE, 256, 0, stream>>>(
      x, WtA, cfA, bufA, N, stpG, gG,
      row, col, E, cnt_in, cnt_out, rank_in, rank_out);
  // 5. scanA(both + dinv) || fold(conv0) from gemm_x stats
  scanA_fold_kernel<<<SB + 64, 256, 0, stream>>>(
      cnt_in, cnt_out, N, partial_in, partial_out, dinv, SB, stpG, gG, W_convs,
      invN, WtB, cfB);
  // 6. scanB (both)
  scanB_kernel<<<1, 256, 0, stream>>>(partial_in, partial_out, SB,
                                      blockoff_in, blockoff_out);
  // 7. scanC (both)
  scanC_kernel<<<SB, 256, 0, stream>>>(cnt_in, cnt_out, N, blockoff_in,
                                       blockoff_out, off_in, off_out, E);
  // 8. place(non-atomic) || gemm(conv0: bufA -> bufB)
  place_gemm_kernel<<<gE + gG, 256, 0, stream>>>(
      row, col, E, rank_in, rank_out, off_in, off_out, dinv, csr_src, slot_in, sout,
      wn, gE, bufA, WtB, cfB, bufB, N);
  // 9. agg(conv0) -> h1 in bufA
  agg_kernel<<<gAgg, 256, 0, stream>>>(bufB, csr_src, wn, off_in, dinv, b_convs, bufA, N);

  // conv 1 (plain agg)
  colstats_kernel<<<CS_BLOCKS, 256, 0, stream>>>(bufA, N, stpX);
  fold256_kernel<<<64, 256, 0, stream>>>(stpX, CS_BLOCKS, W_convs + (size_t)1 * H * H,
                                         nullptr, invN, WtB, cfB);
  gemm_kernel<<<gG, 256, 0, stream>>>(bufA, WtB, cfB, bufB, N, 0);
  agg_kernel<<<gAgg, 256, 0, stream>>>(bufB, csr_src, wn, off_in, dinv,
                                       b_convs + (size_t)1 * H, bufA, N);

  // conv 2 (agg fused with node/edge-attention factor computation)
  colstats_kernel<<<CS_BLOCKS, 256, 0, stream>>>(bufA, N, stpX);
  fold256_kernel<<<64, 256, 0, stream>>>(stpX, CS_BLOCKS, W_convs + (size_t)2 * H * H,
                                         nullptr, invN, WtB, cfB);
  gemm_kernel<<<gG, 256, 0, stream>>>(bufA, WtB, cfB, bufB, N, 0);
  agg_natt_kernel<<<gAgg, 256, 0, stream>>>(bufB, csr_src, wn, off_in, dinv,
                                            b_convs + (size_t)2 * H, W_na, b_na,
                                            W_ea, b_ea, bufA, na01, dp, dq, N);

  // attention
  eatt_xpre_kernel<<<gE + CS_BLOCKS, 256, 0, stream>>>(
      row, col, E, dp, dq, slot_in, sout, att0s, att_r, gE,
      bufA, na01, n4, stpPre);
  degsum_fold2_kernel<<<gN + 128, 256, 0, stream>>>(
      att_r, off_out, na01, f4, N, gN, stpPre, W_ctx, W_obj, invN, Wt2, cf2);
  aggdual_kernel<<<gAgg, 256, 0, stream>>>(bufA, csr_src, att0s, f4,
                                           off_in, bufC, bufD, sumw_c, sumw_o, N);
  gemm2sw_kernel<<<2 * gG, 256, 0, stream>>>(bufC, bufD, Wt2, cf2, b_ctx, b_obj,
                                             sumw_c, sumw_o, N, gG, stpG);
  // xc=bufC, xo=bufD; stats in stpG[0..2*gG)

  // h_co = xc[perm] + xo (+stats) || fold3 heads 0,1
  permadd_fold31_kernel<<<CS_BLOCKS + 128, 256, 0, stream>>>(
      bufC, bufD, perm, bufA, n4, stpCO, stpG, gG, W_fc1, b_fc1, invN, Wt3, cf3);
  // fold3 head 2 (stats from permadd)
  fold256_kernel<<<64, 256, 0, stream>>>(stpCO, CS_BLOCKS, W_fc1 + 2 * (size_t)H * H,
                                         b_fc1 + 2 * H, invN, Wt3 + 2 * (size_t)H * H,
                                         cf3 + 2 * H);
  gemm3_kernel<<<3 * gG, 256, 0, stream>>>(bufC, bufD, bufA, Wt3, cf3, N, gG, stpG);
  fold10x3_kernel<<<3 * NCLS, 128, 0, stream>>>(stpG, gG, W_fc2, b_fc2, invN, W2f, c2f);
  fc2x3_kernel<<<3 * gN, 256, 0, stream>>>(bufC, bufD, bufA, W2f, c2f, out, N, gN);
}